// Round 12
// baseline (320.319 us; speedup 1.0000x reference)
//
#include <hip/hip_runtime.h>
#include <hip/hip_bf16.h>

typedef _Float16 h8 __attribute__((ext_vector_type(8)));
typedef float f4 __attribute__((ext_vector_type(4)));

#define T_ 4
#define B_ 8
#define N_ 512
#define C_ 512
#define H_ 8
#define D_ 64
#define BNR 4096
#define EPSf 1e-5f
#define F16_MIN_NORM 6.1035156e-05f
#define INV4096 0.000244140625f

// ---- x -> (h1 + 2^-12 * h2) f16 split, packed MFMA-fragment-linear ----
__global__ __launch_bounds__(256)
void split_pack_x(const float* __restrict__ in, _Float16* __restrict__ h1,
                  _Float16* __restrict__ h2)
{
    const int gid = blockIdx.x * 256 + threadIdx.x;    // 1048576 h8-groups
    const int lane = gid & 63;
    const int ks = (gid >> 6) & 15;
    const int t = (gid >> 10) & 3;
    const int rt = gid >> 12;
    const int row = rt * 16 + (lane & 15);
    const size_t src = ((size_t)t * BNR + row) * C_ + ks * 32 + (lane >> 4) * 8;
    const float4 x0 = *reinterpret_cast<const float4*>(in + src);
    const float4 x1 = *reinterpret_cast<const float4*>(in + src + 4);
    h8 a, b;
    #pragma unroll
    for (int j = 0; j < 8; ++j) {
        const float xv = (j < 4) ? (&x0.x)[j] : (&x1.x)[j - 4];
        const float hi = (fabsf(xv) >= F16_MIN_NORM) ? xv : 0.0f;
        const _Float16 h = (_Float16)hi;
        const float r = (xv - (float)h) * 4096.0f;
        a[j] = h; b[j] = (_Float16)r;
    }
    *reinterpret_cast<h8*>(h1 + (size_t)gid * 8) = a;
    *reinterpret_cast<h8*>(h2 + (size_t)gid * 8) = b;
}

// ---- W -> split + MFMA-fragment-linear pack ----
__device__ __forceinline__
void pack_w_one(const float* __restrict__ W, _Float16* __restrict__ Wp1,
                _Float16* __restrict__ Wp2, int gid)
{
    const int lane = gid & 63;
    const int ni = (gid >> 6) & 3;
    const int ks = (gid >> 8) & 15;
    const int ct = gid >> 12;
    const int col = ct * 64 + ni * 16 + (lane & 15);
    const int k = ks * 32 + (lane >> 4) * 8;
    const float* src = W + (size_t)col * C_ + k;
    h8 a, b;
    #pragma unroll
    for (int j = 0; j < 8; ++j) {
        const float xv = src[j];
        const float hi = (fabsf(xv) >= F16_MIN_NORM) ? xv : 0.0f;
        const _Float16 h = (_Float16)hi;
        const float r = (xv - (float)h) * 4096.0f;
        a[j] = h; b[j] = (_Float16)r;
    }
    *reinterpret_cast<h8*>(Wp1 + (size_t)gid * 8) = a;
    *reinterpret_cast<h8*>(Wp2 + (size_t)gid * 8) = b;
}

__global__ __launch_bounds__(256)
void pack_w_all(const float* __restrict__ Wq, const float* __restrict__ Wk,
                const float* __restrict__ Wv, const float* __restrict__ Wp,
                _Float16* q1, _Float16* q2, _Float16* k1, _Float16* k2,
                _Float16* v1, _Float16* v2, _Float16* p1, _Float16* p2)
{
    const int g = blockIdx.x * 256 + threadIdx.x;     // 131072
    const int br = g >> 15;
    const int gid = g & 32767;
    if (br == 0)      pack_w_one(Wq, q1, q2, gid);
    else if (br == 1) pack_w_one(Wk, k1, k2, gid);
    else if (br == 2) pack_w_one(Wv, v1, v2, gid);
    else              pack_w_one(Wp, p1, p2, gid);
}

// ---- fused 3-branch GEMM + BN + LIF: block = 32 rows x 64 cols, ALL branches ----
// 8 waves = 4 t-groups (tp=t) x 2 row-halves (wr). A-frags loaded ONCE per
// k-step and fed to q,k,v (36 MFMA/wave/step vs 24 with 1/3 the A traffic).
// W staged to LDS (3 branches x 8KB, dbuf = 48KB). acc = 3x(A,B)x4ni = 96 regs.
// LIF t-chain: 4-stage LDS relay over vst[3][32][64] (reuses W buffers).
__global__ __launch_bounds__(512, 4)
void gemm3_bn_lif(const _Float16* __restrict__ A1p, const _Float16* __restrict__ A2p,
                  const _Float16* __restrict__ Wq1, const _Float16* __restrict__ Wq2,
                  const _Float16* __restrict__ Wk1, const _Float16* __restrict__ Wk2,
                  const _Float16* __restrict__ Wv1, const _Float16* __restrict__ Wv2,
                  const float* __restrict__ biq, const float* __restrict__ gaq,
                  const float* __restrict__ beq, const float* __restrict__ meq,
                  const float* __restrict__ rvq,
                  const float* __restrict__ bik, const float* __restrict__ gak,
                  const float* __restrict__ bek, const float* __restrict__ mek,
                  const float* __restrict__ rvk,
                  const float* __restrict__ biv, const float* __restrict__ gav,
                  const float* __restrict__ bev, const float* __restrict__ mev,
                  const float* __restrict__ rvv,
                  _Float16* __restrict__ oq, _Float16* __restrict__ ok,
                  _Float16* __restrict__ ov)
{
    __shared__ __align__(16) char smem[49152];          // 2 x (3 br x 8KB); relay vst reuse
    const _Float16* W1a[3] = {Wq1, Wk1, Wv1};
    const _Float16* W2a[3] = {Wq2, Wk2, Wv2};
    const float* biasa[3] = {biq, bik, biv};
    const float* gama[3]  = {gaq, gak, gav};
    const float* betaa[3] = {beq, bek, bev};
    const float* meaa[3]  = {meq, mek, mev};
    const float* rvaa[3]  = {rvq, rvk, rvv};
    _Float16* outa[3] = {oq, ok, ov};

    const int id = blockIdx.x;                          // 1024 blocks
    const int bt = (id & 7) * 16 + ((id >> 3) & 15);    // 0..127: same-bt -> same XCD
    const int ct = id >> 7;                             // 0..7
    const int tid = threadIdx.x;
    const int wave = tid >> 6, lane = tid & 63;
    const int tp = wave >> 1, wr = wave & 1;            // tp = own timestep
    const int rt = bt * 2 + wr;                         // 16-row tile index
    const int row0 = bt * 32, col0 = ct * 64;
    const int lr = lane & 15, lk = lane >> 4;

    f4 accA[3][4], accB[3][4];                          // [br][ni]
    #pragma unroll
    for (int br = 0; br < 3; ++br)
        #pragma unroll
        for (int ni = 0; ni < 4; ++ni) { accA[br][ni] = (f4)0.0f; accB[br][ni] = (f4)0.0f; }

    const _Float16* aB1 = A1p + (size_t)rt * 32768 + lane * 8;
    const _Float16* aB2 = A2p + (size_t)rt * 32768 + lane * 8;
    // staging: wave handles 3 slots (one per branch); s_=split, q_=frag (wave-uniform)
    const int s_ = wave >> 2, q_ = wave & 3;
    const _Float16* wsrc[3];
    #pragma unroll
    for (int i = 0; i < 3; ++i)
        wsrc[i] = (s_ ? W2a[i] : W1a[i]) + (size_t)ct * 32768 + q_ * 512 + lane * 8;
    const int wdoff = s_ * 4096 + q_ * 1024;

    auto stageW = [&](int ks, int b) {
        #pragma unroll
        for (int i = 0; i < 3; ++i) {
            __builtin_amdgcn_global_load_lds(
                (const __attribute__((address_space(1))) unsigned int*)(wsrc[i] + ks * 2048),
                (__attribute__((address_space(3))) unsigned int*)(smem + b * 24576 + i * 8192 + wdoff),
                16, 0, 0);
        }
    };

    stageW(0, 0);
    #pragma unroll 2
    for (int ks = 0; ks < 16; ++ks) {
        const int buf = ks & 1;
        __syncthreads();                                // W[buf] ready
        if (ks < 15) stageW(ks + 1, buf ^ 1);
        const h8 a1 = *reinterpret_cast<const h8*>(aB1 + (tp * 16 + ks) * 512);
        const h8 a2 = *reinterpret_cast<const h8*>(aB2 + (tp * 16 + ks) * 512);
        const char* wb = smem + buf * 24576;
        #pragma unroll
        for (int br = 0; br < 3; ++br)
            #pragma unroll
            for (int ni = 0; ni < 4; ++ni) {
                const h8 wf1 = *reinterpret_cast<const h8*>(wb + br * 8192 + ni * 1024 + lane * 16);
                const h8 wf2 = *reinterpret_cast<const h8*>(wb + br * 8192 + 4096 + ni * 1024 + lane * 16);
                accA[br][ni] = __builtin_amdgcn_mfma_f32_16x16x32_f16(a1, wf1, accA[br][ni], 0, 0, 0);
                accB[br][ni] = __builtin_amdgcn_mfma_f32_16x16x32_f16(a1, wf2, accB[br][ni], 0, 0, 0);
                accB[br][ni] = __builtin_amdgcn_mfma_f32_16x16x32_f16(a2, wf1, accB[br][ni], 0, 0, 0);
            }
    }

    // ---- BN + LIF 4-stage relay (t = 0->1->2->3 across wave groups) ----
    float* vst = (float*)smem;                          // [3 br][32 rows][64 cols] fp32
    __syncthreads();                                    // all W reads done
    #pragma unroll
    for (int ts = 0; ts < 4; ++ts) {
        if (tp == ts) {
            #pragma unroll
            for (int br = 0; br < 3; ++br) {
                float sc[4], bi[4], mn[4], be[4];
                #pragma unroll
                for (int ni = 0; ni < 4; ++ni) {
                    const int c = col0 + ni * 16 + lr;
                    sc[ni] = gama[br][c] * (1.0f / sqrtf(rvaa[br][c] + EPSf));
                    bi[ni] = biasa[br][c]; mn[ni] = meaa[br][c]; be[ni] = betaa[br][c];
                }
                #pragma unroll
                for (int ni = 0; ni < 4; ++ni)
                    #pragma unroll
                    for (int r = 0; r < 4; ++r) {
                        const int rl = wr * 16 + lk * 4 + r;    // local row 0..31
                        const int bn = row0 + rl;
                        float vm = (ts == 0) ? 0.0f : vst[(br * 32 + rl) * 64 + ni * 16 + lr];
                        const float res = accA[br][ni][r] + INV4096 * accB[br][ni][r];
                        const float y = ((res + bi[ni]) - mn[ni]) * sc[ni] + be[ni];
                        vm = vm + (y - vm) * 0.5f;
                        const float s = (vm >= 1.0f) ? 1.0f : 0.0f;
                        vm = (s != 0.0f) ? 0.0f : vm;
                        const int b = bn >> 9, n = bn & 511;
                        outa[br][((((size_t)ts * B_ + b) * H_ + ct) * N_ + n) * D_ + ni * 16 + lr] =
                            (_Float16)s;
                        if (ts < 3) vst[(br * 32 + rl) * 64 + ni * 16 + lr] = vm;
                    }
            }
        }
        if (ts < 3) __syncthreads();
    }
}

// ---- p-GEMM (r10 chunked structure, measured good) ----
__global__ __launch_bounds__(512, 4)
void gemm_p_bn_lif(const _Float16* __restrict__ A1p,
                   const _Float16* __restrict__ Wp1, const _Float16* __restrict__ Wp2,
                   const float* __restrict__ bias, const float* __restrict__ gam,
                   const float* __restrict__ bet, const float* __restrict__ mea,
                   const float* __restrict__ rva, float* __restrict__ out_plain)
{
    __shared__ __align__(16) char wsm[65536];
    const int id = blockIdx.x;
    const int bt = (id & 7) * 8 + ((id >> 3) & 7);
    const int ct = id >> 6;
    const int tid = threadIdx.x;
    const int wave = tid >> 6, lane = tid & 63;
    const int tp = wave & 1, wr = wave >> 1;
    const int rt = bt * 4 + wr;
    const int row0 = bt * 64, col0 = ct * 64;
    const int lr = lane & 15, lk = lane >> 4;

    f4 accA[2][4], accB[2][4];
    #pragma unroll
    for (int ti = 0; ti < 2; ++ti)
        #pragma unroll
        for (int ni = 0; ni < 4; ++ni) { accA[ti][ni] = (f4)0.0f; accB[ti][ni] = (f4)0.0f; }

    const _Float16* aB1 = A1p + (size_t)rt * 32768 + lane * 8;
    const int s_ = wave >> 2, q_ = wave & 3;
    const _Float16* wsrc = (s_ ? Wp2 : Wp1) + (size_t)ct * 32768 + q_ * 512 + lane * 8;
    const int wdoff = s_ * 4096 + q_ * 1024;

    auto stageChunk = [&](int c, int b) {
        #pragma unroll
        for (int ksl = 0; ksl < 4; ++ksl) {
            __builtin_amdgcn_global_load_lds(
                (const __attribute__((address_space(1))) unsigned int*)(wsrc + (c * 4 + ksl) * 2048),
                (__attribute__((address_space(3))) unsigned int*)(wsm + b * 32768 + ksl * 8192 + wdoff),
                16, 0, 0);
        }
    };

    stageChunk(0, 0);
    #pragma unroll
    for (int c = 0; c < 4; ++c) {
        const int buf = c & 1;
        __syncthreads();
        if (c < 3) stageChunk(c + 1, buf ^ 1);
        #pragma unroll
        for (int ksl = 0; ksl < 4; ++ksl) {
            const int ks = c * 4 + ksl;
            h8 a1[2];
            #pragma unroll
            for (int ti = 0; ti < 2; ++ti) {
                const int t = tp * 2 + ti;
                a1[ti] = *reinterpret_cast<const h8*>(aB1 + (t * 16 + ks) * 512);
            }
            const char* wb = wsm + buf * 32768 + ksl * 8192;
            #pragma unroll
            for (int ni = 0; ni < 4; ++ni) {
                const h8 wf1 = *reinterpret_cast<const h8*>(wb + ni * 1024 + lane * 16);
                const h8 wf2 = *reinterpret_cast<const h8*>(wb + 4096 + ni * 1024 + lane * 16);
                #pragma unroll
                for (int ti = 0; ti < 2; ++ti) {
                    accA[ti][ni] = __builtin_amdgcn_mfma_f32_16x16x32_f16(a1[ti], wf1, accA[ti][ni], 0, 0, 0);
                    accB[ti][ni] = __builtin_amdgcn_mfma_f32_16x16x32_f16(a1[ti], wf2, accB[ti][ni], 0, 0, 0);
                }
            }
        }
    }

    float* vst = (float*)wsm;
    float sc[4], bi[4], mn[4], be[4];
    #pragma unroll
    for (int ni = 0; ni < 4; ++ni) {
        const int c = col0 + ni * 16 + lr;
        sc[ni] = gam[c] * (1.0f / sqrtf(rva[c] + EPSf));
        bi[ni] = bias[c]; mn[ni] = mea[c]; be[ni] = bet[c];
    }
    __syncthreads();
    if (tp == 0) {
        #pragma unroll
        for (int ni = 0; ni < 4; ++ni)
            #pragma unroll
            for (int r = 0; r < 4; ++r) {
                const int rl = wr * 16 + lk * 4 + r;
                const int bn = row0 + rl;
                float vm = 0.0f;
                #pragma unroll
                for (int ti = 0; ti < 2; ++ti) {        // t = 0,1
                    const float res = accA[ti][ni][r] + INV4096 * accB[ti][ni][r];
                    const float y = ((res + bi[ni]) - mn[ni]) * sc[ni] + be[ni];
                    vm = vm + (y - vm) * 0.5f;
                    const float s = (vm >= 1.0f) ? 1.0f : 0.0f;
                    vm = (s != 0.0f) ? 0.0f : vm;
                    out_plain[((size_t)ti * BNR + bn) * C_ + col0 + ni * 16 + lr] = s;
                }
                vst[rl * 64 + ni * 16 + lr] = vm;
            }
    }
    __syncthreads();
    if (tp == 1) {
        #pragma unroll
        for (int ni = 0; ni < 4; ++ni)
            #pragma unroll
            for (int r = 0; r < 4; ++r) {
                const int rl = wr * 16 + lk * 4 + r;
                const int bn = row0 + rl;
                float vm = vst[rl * 64 + ni * 16 + lr];
                #pragma unroll
                for (int ti = 0; ti < 2; ++ti) {        // t = 2,3
                    const float res = accA[ti][ni][r] + INV4096 * accB[ti][ni][r];
                    const float y = ((res + bi[ni]) - mn[ni]) * sc[ni] + be[ni];
                    vm = vm + (y - vm) * 0.5f;
                    const float s = (vm >= 1.0f) ? 1.0f : 0.0f;
                    vm = (s != 0.0f) ? 0.0f : vm;
                    out_plain[((size_t)(2 + ti) * BNR + bn) * C_ + col0 + ni * 16 + lr] = s;
                }
            }
    }
}

// ---- kvT[d2][d1] = sum_n k[n,d1]*v[n,d2] per (t,b,h); f16 exact (ints <= 512) ----
__global__ __launch_bounds__(256)
void ktv_kernel(const _Float16* __restrict__ sk, const _Float16* __restrict__ sv,
                _Float16* __restrict__ kvT)
{
    __shared__ _Float16 kl[64][64];
    __shared__ _Float16 vl[64][64];
    const int tbh = blockIdx.x;
    const int tid = threadIdx.x;
    const int tx = tid & 15, ty = tid >> 4;
    const size_t base = (size_t)tbh * N_ * D_;
    float acc[4][4] = {};
    for (int n0 = 0; n0 < N_; n0 += 64) {
        __syncthreads();
        #pragma unroll
        for (int p = 0; p < 2; ++p) {
            const int idx = tid + p * 256;
            const int r = idx >> 3, c8 = (idx & 7) * 8;
            *reinterpret_cast<float4*>(&kl[r][c8]) =
                *reinterpret_cast<const float4*>(&sk[base + (size_t)(n0 + r) * D_ + c8]);
            *reinterpret_cast<float4*>(&vl[r][c8]) =
                *reinterpret_cast<const float4*>(&sv[base + (size_t)(n0 + r) * D_ + c8]);
        }
        __syncthreads();
        for (int nn = 0; nn < 64; ++nn) {
            float a[4], b[4];
            #pragma unroll
            for (int i = 0; i < 4; ++i) a[i] = (float)kl[nn][ty * 4 + i];
            #pragma unroll
            for (int j = 0; j < 4; ++j) b[j] = (float)vl[nn][tx * 4 + j];
            #pragma unroll
            for (int i = 0; i < 4; ++i)
                #pragma unroll
                for (int j = 0; j < 4; ++j)
                    acc[i][j] = fmaf(a[i], b[j], acc[i][j]);
        }
    }
    _Float16* out = kvT + (size_t)tbh * 4096;           // [d2][d1] (transposed)
    #pragma unroll
    for (int i = 0; i < 4; ++i)
        #pragma unroll
        for (int j = 0; j < 4; ++j)
            out[(tx * 4 + j) * 64 + ty * 4 + i] = (_Float16)acc[i][j];
}

// ---- o = 0.125 * q @ kv via MFMA (exact integer arith), fused attn-LIF ----
__global__ __launch_bounds__(256)
void qkv_mfma_lif(const _Float16* __restrict__ sq, const _Float16* __restrict__ kvT,
                  _Float16* __restrict__ osp)
{
    __shared__ __align__(16) char ot[8192];             // [64 rows][128B], swizzled
    const int nt = blockIdx.x, b = blockIdx.y, h = blockIdx.z;
    const int tid = threadIdx.x;
    const int wv = tid >> 6, lane = tid & 63;
    const int lr = lane & 15, lk = lane >> 4;
    const int n0 = nt * 64;

    f4 vst[4];
    #pragma unroll
    for (int ni = 0; ni < 4; ++ni) vst[ni] = (f4)0.0f;

    for (int t = 0; t < T_; ++t) {
        const int tbh = (t * B_ + b) * H_ + h;
        const _Float16* qb = sq + ((size_t)tbh * N_ + n0 + wv * 16 + lr) * D_;
        const h8 a0 = *reinterpret_cast<const h8*>(qb + lk * 8);
        const h8 a1 = *reinterpret_cast<const h8*>(qb + 32 + lk * 8);
        const _Float16* kb = kvT + (size_t)tbh * 4096 + lr * 64 + lk * 8;
        f4 acc[4];
        #pragma unroll
        for (int ni = 0; ni < 4; ++ni) {
            const _Float16* kbn = kb + ni * 1024;
            const h8 b0 = *reinterpret_cast<const h8*>(kbn);
            const h8 b1 = *reinterpret_cast<const h8*>(kbn + 32);
            f4 a = (f4)0.0f;
            a = __builtin_amdgcn_mfma_f32_16x16x32_f16(a0, b0, a, 0, 0, 0);
            a = __builtin_amdgcn_mfma_f32_16x16x32_f16(a1, b1, a, 0, 0, 0);
            acc[ni] = a;
        }
        #pragma unroll
        for (int ni = 0; ni < 4; ++ni)
            #pragma unroll
            for (int r = 0; r < 4; ++r) {
                const float y = 0.125f * acc[ni][r];    // exact
                float vv = vst[ni][r];
                vv = vv + (y - vv) * 0.5f;
                const float s = (vv >= 0.5f) ? 1.0f : 0.0f;
                vst[ni][r] = (s != 0.0f) ? 0.0f : vv;
                const int row = wv * 16 + lk * 4 + r;
                const int colb = (ni * 16 + lr) * 2;
                *(_Float16*)(ot + row * 128 + (colb ^ ((row & 7) << 4))) = (_Float16)s;
            }
        const int rt = b * 32 + nt * 4 + wv;
        #pragma unroll
        for (int ks1 = 0; ks1 < 2; ++ks1) {
            const int row = wv * 16 + lr;
            const int colb = ks1 * 64 + lk * 16;
            const h8 vvv = *reinterpret_cast<const h8*>(ot + row * 128 + (colb ^ ((row & 7) << 4)));
            *reinterpret_cast<h8*>(osp +
                ((((size_t)rt * 4 + t) * 16 + h * 2 + ks1) * 64 + lane) * 8) = vvv;
        }
    }
}

extern "C" void kernel_launch(void* const* d_in, const int* in_sizes, int n_in,
                              void* d_out, int out_size, void* d_ws, size_t ws_size,
                              hipStream_t stream)
{
    const float* x = (const float*)d_in[0];
    const float *W[4], *bia[4], *gam[4], *bet[4], *mea[4], *rva[4];
    for (int br = 0; br < 4; ++br) {
        W[br]   = (const float*)d_in[1 + 6 * br + 0];
        bia[br] = (const float*)d_in[1 + 6 * br + 1];
        gam[br] = (const float*)d_in[1 + 6 * br + 2];
        bet[br] = (const float*)d_in[1 + 6 * br + 3];
        mea[br] = (const float*)d_in[1 + 6 * br + 4];
        rva[br] = (const float*)d_in[1 + 6 * br + 5];
    }
    char* ws = (char*)d_ws;
    _Float16* x1 = (_Float16*)(ws + 0);
    _Float16* x2 = (_Float16*)(ws + 16777216);
    _Float16* sq = (_Float16*)(ws + 33554432);
    _Float16* sk = (_Float16*)(ws + 50331648);
    _Float16* sv = (_Float16*)(ws + 67108864);
    _Float16* w1[4], *w2[4];
    for (int br = 0; br < 4; ++br) {
        w1[br] = (_Float16*)(ws + 83886080 + (size_t)br * 1048576);
        w2[br] = (_Float16*)(ws + 83886080 + (size_t)br * 1048576 + 524288);
    }
    _Float16* kvT = (_Float16*)(ws + 16777216);  // aliases x2 (dead after gemm3)
    _Float16* osp = (_Float16*)(ws + 0);         // aliases x1 (dead after gemm3)

    dim3 blk(256);
    split_pack_x<<<dim3(4096), blk, 0, stream>>>(x, x1, x2);
    pack_w_all<<<dim3(512), blk, 0, stream>>>(W[0], W[1], W[2], W[3],
        w1[0], w2[0], w1[1], w2[1], w1[2], w2[2], w1[3], w2[3]);

    gemm3_bn_lif<<<dim3(1024), dim3(512), 0, stream>>>(x1, x2,
        w1[0], w2[0], w1[1], w2[1], w1[2], w2[2],
        bia[0], gam[0], bet[0], mea[0], rva[0],
        bia[1], gam[1], bet[1], mea[1], rva[1],
        bia[2], gam[2], bet[2], mea[2], rva[2],
        sq, sk, sv);

    ktv_kernel<<<dim3(T_ * B_ * H_), blk, 0, stream>>>(sk, sv, kvT);
    qkv_mfma_lif<<<dim3(N_ / 64, B_, H_), blk, 0, stream>>>(sq, kvT, osp);

    gemm_p_bn_lif<<<dim3(512), dim3(512), 0, stream>>>(osp, w1[3], w2[3],
        bia[3], gam[3], bet[3], mea[3], rva[3], (float*)d_out);
}

// Round 13
// 168.822 us; speedup vs baseline: 1.8974x; 1.8974x over previous
//
#include <hip/hip_runtime.h>
#include <hip/hip_bf16.h>

typedef _Float16 h8 __attribute__((ext_vector_type(8)));
typedef float f4 __attribute__((ext_vector_type(4)));

#define T_ 4
#define B_ 8
#define N_ 512
#define C_ 512
#define H_ 8
#define D_ 64
#define BNR 4096
#define EPSf 1e-5f
#define F16_MIN_NORM 6.1035156e-05f
#define INV4096 0.000244140625f

// ---- x -> (h1 + 2^-12 * h2) f16 split, packed MFMA-fragment-linear ----
__global__ __launch_bounds__(256)
void split_pack_x(const float* __restrict__ in, _Float16* __restrict__ h1,
                  _Float16* __restrict__ h2)
{
    const int gid = blockIdx.x * 256 + threadIdx.x;    // 1048576 h8-groups
    const int lane = gid & 63;
    const int ks = (gid >> 6) & 15;
    const int t = (gid >> 10) & 3;
    const int rt = gid >> 12;
    const int row = rt * 16 + (lane & 15);
    const size_t src = ((size_t)t * BNR + row) * C_ + ks * 32 + (lane >> 4) * 8;
    const float4 x0 = *reinterpret_cast<const float4*>(in + src);
    const float4 x1 = *reinterpret_cast<const float4*>(in + src + 4);
    h8 a, b;
    #pragma unroll
    for (int j = 0; j < 8; ++j) {
        const float xv = (j < 4) ? (&x0.x)[j] : (&x1.x)[j - 4];
        const float hi = (fabsf(xv) >= F16_MIN_NORM) ? xv : 0.0f;
        const _Float16 h = (_Float16)hi;
        const float r = (xv - (float)h) * 4096.0f;
        a[j] = h; b[j] = (_Float16)r;
    }
    *reinterpret_cast<h8*>(h1 + (size_t)gid * 8) = a;
    *reinterpret_cast<h8*>(h2 + (size_t)gid * 8) = b;
}

// ---- W -> split + MFMA-fragment-linear pack ----
__device__ __forceinline__
void pack_w_one(const float* __restrict__ W, _Float16* __restrict__ Wp1,
                _Float16* __restrict__ Wp2, int gid)
{
    const int lane = gid & 63;
    const int ni = (gid >> 6) & 3;
    const int ks = (gid >> 8) & 15;
    const int ct = gid >> 12;
    const int col = ct * 64 + ni * 16 + (lane & 15);
    const int k = ks * 32 + (lane >> 4) * 8;
    const float* src = W + (size_t)col * C_ + k;
    h8 a, b;
    #pragma unroll
    for (int j = 0; j < 8; ++j) {
        const float xv = src[j];
        const float hi = (fabsf(xv) >= F16_MIN_NORM) ? xv : 0.0f;
        const _Float16 h = (_Float16)hi;
        const float r = (xv - (float)h) * 4096.0f;
        a[j] = h; b[j] = (_Float16)r;
    }
    *reinterpret_cast<h8*>(Wp1 + (size_t)gid * 8) = a;
    *reinterpret_cast<h8*>(Wp2 + (size_t)gid * 8) = b;
}

__global__ __launch_bounds__(256)
void pack_w_all(const float* __restrict__ Wq, const float* __restrict__ Wk,
                const float* __restrict__ Wv, const float* __restrict__ Wp,
                _Float16* q1, _Float16* q2, _Float16* k1, _Float16* k2,
                _Float16* v1, _Float16* v2, _Float16* p1, _Float16* p2)
{
    const int g = blockIdx.x * 256 + threadIdx.x;     // 131072
    const int br = g >> 15;
    const int gid = g & 32767;
    if (br == 0)      pack_w_one(Wq, q1, q2, gid);
    else if (br == 1) pack_w_one(Wk, k1, k2, gid);
    else if (br == 2) pack_w_one(Wv, v1, v2, gid);
    else              pack_w_one(Wp, p1, p2, gid);
}

// ---- gemm3 (r9/r11 structure + A register-prefetch across the barrier) ----
// 512 thr, 8 waves = (tp) x (wr). W staged per-k-step to 16KB LDS dbuf.
// A[ks+1] loaded into regs right after stageW(ks+1): the load completes under
// step-ks MFMAs, so no per-step exposed L2 latency (syncthreads is a fence and
// would otherwise block hoisting). Fully unrolled -> rotation = renaming.
__global__ __launch_bounds__(512, 4)
void gemm3_bn_lif(const _Float16* __restrict__ A1p, const _Float16* __restrict__ A2p,
                  const _Float16* __restrict__ Wq1, const _Float16* __restrict__ Wq2,
                  const _Float16* __restrict__ Wk1, const _Float16* __restrict__ Wk2,
                  const _Float16* __restrict__ Wv1, const _Float16* __restrict__ Wv2,
                  const float* __restrict__ biq, const float* __restrict__ gaq,
                  const float* __restrict__ beq, const float* __restrict__ meq,
                  const float* __restrict__ rvq,
                  const float* __restrict__ bik, const float* __restrict__ gak,
                  const float* __restrict__ bek, const float* __restrict__ mek,
                  const float* __restrict__ rvk,
                  const float* __restrict__ biv, const float* __restrict__ gav,
                  const float* __restrict__ bev, const float* __restrict__ mev,
                  const float* __restrict__ rvv,
                  _Float16* __restrict__ oq, _Float16* __restrict__ ok,
                  _Float16* __restrict__ ov)
{
    __shared__ __align__(16) char wsm[16384];           // 2 x 8KB W dbuf; reused as v-state
    const int br = blockIdx.y;
    const _Float16* W1 = (br == 0) ? Wq1 : (br == 1) ? Wk1 : Wv1;
    const _Float16* W2 = (br == 0) ? Wq2 : (br == 1) ? Wk2 : Wv2;
    const float* bias = (br == 0) ? biq : (br == 1) ? bik : biv;
    const float* gam  = (br == 0) ? gaq : (br == 1) ? gak : gav;
    const float* bet  = (br == 0) ? beq : (br == 1) ? bek : bev;
    const float* mea  = (br == 0) ? meq : (br == 1) ? mek : mev;
    const float* rva  = (br == 0) ? rvq : (br == 1) ? rvk : rvv;
    _Float16* out = (br == 0) ? oq : (br == 1) ? ok : ov;

    const int id = blockIdx.x;
    const int bt = (id & 7) * 8 + ((id >> 3) & 7);      // XCD-aware swizzle
    const int ct = id >> 6;
    const int tid = threadIdx.x;
    const int wave = tid >> 6, lane = tid & 63;
    const int tp = wave & 1, wr = wave >> 1;
    const int rt = bt * 4 + wr;
    const int row0 = bt * 64, col0 = ct * 64;
    const int lr = lane & 15, lk = lane >> 4;

    f4 accA[2][4], accB[2][4];
    #pragma unroll
    for (int ti = 0; ti < 2; ++ti)
        #pragma unroll
        for (int ni = 0; ni < 4; ++ni) { accA[ti][ni] = (f4)0.0f; accB[ti][ni] = (f4)0.0f; }

    const _Float16* aB1 = A1p + (size_t)rt * 32768 + lane * 8;
    const _Float16* aB2 = A2p + (size_t)rt * 32768 + lane * 8;
    const int s_ = wave >> 2, q_ = wave & 3;
    const _Float16* wsrc = (s_ ? W2 : W1) + (size_t)ct * 32768 + q_ * 512 + lane * 8;
    const int wdoff = s_ * 4096 + q_ * 1024;

    auto stageW = [&](int ks, int b) {
        __builtin_amdgcn_global_load_lds(
            (const __attribute__((address_space(1))) unsigned int*)(wsrc + ks * 2048),
            (__attribute__((address_space(3))) unsigned int*)(wsm + b * 8192 + wdoff),
            16, 0, 0);
    };

    // prologue: stage W[0] and prefetch A[0] into registers
    stageW(0, 0);
    h8 a1c[2], a2c[2];
    #pragma unroll
    for (int ti = 0; ti < 2; ++ti) {
        const int t = tp * 2 + ti;
        a1c[ti] = *reinterpret_cast<const h8*>(aB1 + (t * 16 + 0) * 512);
        a2c[ti] = *reinterpret_cast<const h8*>(aB2 + (t * 16 + 0) * 512);
    }
    #pragma unroll
    for (int ks = 0; ks < 16; ++ks) {
        const int buf = ks & 1;
        __syncthreads();                                // W[buf]+A[ks] drained
        h8 a1n[2], a2n[2];
        if (ks < 15) {
            stageW(ks + 1, buf ^ 1);
            #pragma unroll
            for (int ti = 0; ti < 2; ++ti) {            // prefetch A[ks+1]
                const int t = tp * 2 + ti;
                a1n[ti] = *reinterpret_cast<const h8*>(aB1 + (t * 16 + ks + 1) * 512);
                a2n[ti] = *reinterpret_cast<const h8*>(aB2 + (t * 16 + ks + 1) * 512);
            }
        }
        const char* wb = wsm + buf * 8192;
        #pragma unroll
        for (int ni = 0; ni < 4; ++ni) {
            const h8 wf1 = *reinterpret_cast<const h8*>(wb + ni * 1024 + lane * 16);
            const h8 wf2 = *reinterpret_cast<const h8*>(wb + 4096 + ni * 1024 + lane * 16);
            #pragma unroll
            for (int ti = 0; ti < 2; ++ti) {
                accA[ti][ni] = __builtin_amdgcn_mfma_f32_16x16x32_f16(a1c[ti], wf1, accA[ti][ni], 0, 0, 0);
                accB[ti][ni] = __builtin_amdgcn_mfma_f32_16x16x32_f16(a1c[ti], wf2, accB[ti][ni], 0, 0, 0);
                accB[ti][ni] = __builtin_amdgcn_mfma_f32_16x16x32_f16(a2c[ti], wf1, accB[ti][ni], 0, 0, 0);
            }
        }
        if (ks < 15) {
            #pragma unroll
            for (int ti = 0; ti < 2; ++ti) { a1c[ti] = a1n[ti]; a2c[ti] = a2n[ti]; }
        }
    }

    // ---- BN + LIF epilogue with t-split handoff via LDS ----
    float* vst = (float*)wsm;
    float sc[4], bi[4], mn[4], be[4];
    #pragma unroll
    for (int ni = 0; ni < 4; ++ni) {
        const int c = col0 + ni * 16 + lr;
        sc[ni] = gam[c] * (1.0f / sqrtf(rva[c] + EPSf));
        bi[ni] = bias[c]; mn[ni] = mea[c]; be[ni] = bet[c];
    }
    __syncthreads();
    if (tp == 0) {
        #pragma unroll
        for (int ni = 0; ni < 4; ++ni)
            #pragma unroll
            for (int r = 0; r < 4; ++r) {
                const int rl = wr * 16 + lk * 4 + r;
                const int bn = row0 + rl;
                float vm = 0.0f;
                #pragma unroll
                for (int ti = 0; ti < 2; ++ti) {        // t = 0,1
                    const float res = accA[ti][ni][r] + INV4096 * accB[ti][ni][r];
                    const float y = ((res + bi[ni]) - mn[ni]) * sc[ni] + be[ni];
                    vm = vm + (y - vm) * 0.5f;
                    const float s = (vm >= 1.0f) ? 1.0f : 0.0f;
                    vm = (s != 0.0f) ? 0.0f : vm;
                    const int b = bn >> 9, n = bn & 511;
                    out[((((size_t)ti * B_ + b) * H_ + ct) * N_ + n) * D_ + ni * 16 + lr] =
                        (_Float16)s;
                }
                vst[rl * 64 + ni * 16 + lr] = vm;
            }
    }
    __syncthreads();
    if (tp == 1) {
        #pragma unroll
        for (int ni = 0; ni < 4; ++ni)
            #pragma unroll
            for (int r = 0; r < 4; ++r) {
                const int rl = wr * 16 + lk * 4 + r;
                const int bn = row0 + rl;
                float vm = vst[rl * 64 + ni * 16 + lr];
                #pragma unroll
                for (int ti = 0; ti < 2; ++ti) {        // t = 2,3
                    const float res = accA[ti][ni][r] + INV4096 * accB[ti][ni][r];
                    const float y = ((res + bi[ni]) - mn[ni]) * sc[ni] + be[ni];
                    vm = vm + (y - vm) * 0.5f;
                    const float s = (vm >= 1.0f) ? 1.0f : 0.0f;
                    vm = (s != 0.0f) ? 0.0f : vm;
                    const int b = bn >> 9, n = bn & 511;
                    out[((((size_t)(2 + ti) * B_ + b) * H_ + ct) * N_ + n) * D_ + ni * 16 + lr] =
                        (_Float16)s;
                }
            }
    }
}

// ---- p-GEMM (r10 chunked structure, measured good) ----
__global__ __launch_bounds__(512, 4)
void gemm_p_bn_lif(const _Float16* __restrict__ A1p,
                   const _Float16* __restrict__ Wp1, const _Float16* __restrict__ Wp2,
                   const float* __restrict__ bias, const float* __restrict__ gam,
                   const float* __restrict__ bet, const float* __restrict__ mea,
                   const float* __restrict__ rva, float* __restrict__ out_plain)
{
    __shared__ __align__(16) char wsm[65536];
    const int id = blockIdx.x;
    const int bt = (id & 7) * 8 + ((id >> 3) & 7);
    const int ct = id >> 6;
    const int tid = threadIdx.x;
    const int wave = tid >> 6, lane = tid & 63;
    const int tp = wave & 1, wr = wave >> 1;
    const int rt = bt * 4 + wr;
    const int row0 = bt * 64, col0 = ct * 64;
    const int lr = lane & 15, lk = lane >> 4;

    f4 accA[2][4], accB[2][4];
    #pragma unroll
    for (int ti = 0; ti < 2; ++ti)
        #pragma unroll
        for (int ni = 0; ni < 4; ++ni) { accA[ti][ni] = (f4)0.0f; accB[ti][ni] = (f4)0.0f; }

    const _Float16* aB1 = A1p + (size_t)rt * 32768 + lane * 8;
    const int s_ = wave >> 2, q_ = wave & 3;
    const _Float16* wsrc = (s_ ? Wp2 : Wp1) + (size_t)ct * 32768 + q_ * 512 + lane * 8;
    const int wdoff = s_ * 4096 + q_ * 1024;

    auto stageChunk = [&](int c, int b) {
        #pragma unroll
        for (int ksl = 0; ksl < 4; ++ksl) {
            __builtin_amdgcn_global_load_lds(
                (const __attribute__((address_space(1))) unsigned int*)(wsrc + (c * 4 + ksl) * 2048),
                (__attribute__((address_space(3))) unsigned int*)(wsm + b * 32768 + ksl * 8192 + wdoff),
                16, 0, 0);
        }
    };

    stageChunk(0, 0);
    #pragma unroll
    for (int c = 0; c < 4; ++c) {
        const int buf = c & 1;
        __syncthreads();
        if (c < 3) stageChunk(c + 1, buf ^ 1);
        #pragma unroll
        for (int ksl = 0; ksl < 4; ++ksl) {
            const int ks = c * 4 + ksl;
            h8 a1[2];
            #pragma unroll
            for (int ti = 0; ti < 2; ++ti) {
                const int t = tp * 2 + ti;
                a1[ti] = *reinterpret_cast<const h8*>(aB1 + (t * 16 + ks) * 512);
            }
            const char* wb = wsm + buf * 32768 + ksl * 8192;
            #pragma unroll
            for (int ni = 0; ni < 4; ++ni) {
                const h8 wf1 = *reinterpret_cast<const h8*>(wb + ni * 1024 + lane * 16);
                const h8 wf2 = *reinterpret_cast<const h8*>(wb + 4096 + ni * 1024 + lane * 16);
                #pragma unroll
                for (int ti = 0; ti < 2; ++ti) {
                    accA[ti][ni] = __builtin_amdgcn_mfma_f32_16x16x32_f16(a1[ti], wf1, accA[ti][ni], 0, 0, 0);
                    accB[ti][ni] = __builtin_amdgcn_mfma_f32_16x16x32_f16(a1[ti], wf2, accB[ti][ni], 0, 0, 0);
                }
            }
        }
    }

    float* vst = (float*)wsm;
    float sc[4], bi[4], mn[4], be[4];
    #pragma unroll
    for (int ni = 0; ni < 4; ++ni) {
        const int c = col0 + ni * 16 + lr;
        sc[ni] = gam[c] * (1.0f / sqrtf(rva[c] + EPSf));
        bi[ni] = bias[c]; mn[ni] = mea[c]; be[ni] = bet[c];
    }
    __syncthreads();
    if (tp == 0) {
        #pragma unroll
        for (int ni = 0; ni < 4; ++ni)
            #pragma unroll
            for (int r = 0; r < 4; ++r) {
                const int rl = wr * 16 + lk * 4 + r;
                const int bn = row0 + rl;
                float vm = 0.0f;
                #pragma unroll
                for (int ti = 0; ti < 2; ++ti) {        // t = 0,1
                    const float res = accA[ti][ni][r] + INV4096 * accB[ti][ni][r];
                    const float y = ((res + bi[ni]) - mn[ni]) * sc[ni] + be[ni];
                    vm = vm + (y - vm) * 0.5f;
                    const float s = (vm >= 1.0f) ? 1.0f : 0.0f;
                    vm = (s != 0.0f) ? 0.0f : vm;
                    out_plain[((size_t)ti * BNR + bn) * C_ + col0 + ni * 16 + lr] = s;
                }
                vst[rl * 64 + ni * 16 + lr] = vm;
            }
    }
    __syncthreads();
    if (tp == 1) {
        #pragma unroll
        for (int ni = 0; ni < 4; ++ni)
            #pragma unroll
            for (int r = 0; r < 4; ++r) {
                const int rl = wr * 16 + lk * 4 + r;
                const int bn = row0 + rl;
                float vm = vst[rl * 64 + ni * 16 + lr];
                #pragma unroll
                for (int ti = 0; ti < 2; ++ti) {        // t = 2,3
                    const float res = accA[ti][ni][r] + INV4096 * accB[ti][ni][r];
                    const float y = ((res + bi[ni]) - mn[ni]) * sc[ni] + be[ni];
                    vm = vm + (y - vm) * 0.5f;
                    const float s = (vm >= 1.0f) ? 1.0f : 0.0f;
                    vm = (s != 0.0f) ? 0.0f : vm;
                    out_plain[((size_t)(2 + ti) * BNR + bn) * C_ + col0 + ni * 16 + lr] = s;
                }
            }
    }
}

// ---- kvT[d2][d1] = sum_n k[n,d1]*v[n,d2] per (t,b,h); f16 exact (ints <= 512) ----
__global__ __launch_bounds__(256)
void ktv_kernel(const _Float16* __restrict__ sk, const _Float16* __restrict__ sv,
                _Float16* __restrict__ kvT)
{
    __shared__ _Float16 kl[64][64];
    __shared__ _Float16 vl[64][64];
    const int tbh = blockIdx.x;
    const int tid = threadIdx.x;
    const int tx = tid & 15, ty = tid >> 4;
    const size_t base = (size_t)tbh * N_ * D_;
    float acc[4][4] = {};
    for (int n0 = 0; n0 < N_; n0 += 64) {
        __syncthreads();
        #pragma unroll
        for (int p = 0; p < 2; ++p) {
            const int idx = tid + p * 256;
            const int r = idx >> 3, c8 = (idx & 7) * 8;
            *reinterpret_cast<float4*>(&kl[r][c8]) =
                *reinterpret_cast<const float4*>(&sk[base + (size_t)(n0 + r) * D_ + c8]);
            *reinterpret_cast<float4*>(&vl[r][c8]) =
                *reinterpret_cast<const float4*>(&sv[base + (size_t)(n0 + r) * D_ + c8]);
        }
        __syncthreads();
        for (int nn = 0; nn < 64; ++nn) {
            float a[4], b[4];
            #pragma unroll
            for (int i = 0; i < 4; ++i) a[i] = (float)kl[nn][ty * 4 + i];
            #pragma unroll
            for (int j = 0; j < 4; ++j) b[j] = (float)vl[nn][tx * 4 + j];
            #pragma unroll
            for (int i = 0; i < 4; ++i)
                #pragma unroll
                for (int j = 0; j < 4; ++j)
                    acc[i][j] = fmaf(a[i], b[j], acc[i][j]);
        }
    }
    _Float16* out = kvT + (size_t)tbh * 4096;           // [d2][d1] (transposed)
    #pragma unroll
    for (int i = 0; i < 4; ++i)
        #pragma unroll
        for (int j = 0; j < 4; ++j)
            out[(tx * 4 + j) * 64 + ty * 4 + i] = (_Float16)acc[i][j];
}

// ---- o = 0.125 * q @ kv via MFMA (exact integer arith), fused attn-LIF ----
__global__ __launch_bounds__(256)
void qkv_mfma_lif(const _Float16* __restrict__ sq, const _Float16* __restrict__ kvT,
                  _Float16* __restrict__ osp)
{
    __shared__ __align__(16) char ot[8192];             // [64 rows][128B], swizzled
    const int nt = blockIdx.x, b = blockIdx.y, h = blockIdx.z;
    const int tid = threadIdx.x;
    const int wv = tid >> 6, lane = tid & 63;
    const int lr = lane & 15, lk = lane >> 4;
    const int n0 = nt * 64;

    f4 vst[4];
    #pragma unroll
    for (int ni = 0; ni < 4; ++ni) vst[ni] = (f4)0.0f;

    for (int t = 0; t < T_; ++t) {
        const int tbh = (t * B_ + b) * H_ + h;
        const _Float16* qb = sq + ((size_t)tbh * N_ + n0 + wv * 16 + lr) * D_;
        const h8 a0 = *reinterpret_cast<const h8*>(qb + lk * 8);
        const h8 a1 = *reinterpret_cast<const h8*>(qb + 32 + lk * 8);
        const _Float16* kb = kvT + (size_t)tbh * 4096 + lr * 64 + lk * 8;
        f4 acc[4];
        #pragma unroll
        for (int ni = 0; ni < 4; ++ni) {
            const _Float16* kbn = kb + ni * 1024;
            const h8 b0 = *reinterpret_cast<const h8*>(kbn);
            const h8 b1 = *reinterpret_cast<const h8*>(kbn + 32);
            f4 a = (f4)0.0f;
            a = __builtin_amdgcn_mfma_f32_16x16x32_f16(a0, b0, a, 0, 0, 0);
            a = __builtin_amdgcn_mfma_f32_16x16x32_f16(a1, b1, a, 0, 0, 0);
            acc[ni] = a;
        }
        #pragma unroll
        for (int ni = 0; ni < 4; ++ni)
            #pragma unroll
            for (int r = 0; r < 4; ++r) {
                const float y = 0.125f * acc[ni][r];    // exact
                float vv = vst[ni][r];
                vv = vv + (y - vv) * 0.5f;
                const float s = (vv >= 0.5f) ? 1.0f : 0.0f;
                vst[ni][r] = (s != 0.0f) ? 0.0f : vv;
                const int row = wv * 16 + lk * 4 + r;
                const int colb = (ni * 16 + lr) * 2;
                *(_Float16*)(ot + row * 128 + (colb ^ ((row & 7) << 4))) = (_Float16)s;
            }
        const int rt = b * 32 + nt * 4 + wv;
        #pragma unroll
        for (int ks1 = 0; ks1 < 2; ++ks1) {
            const int row = wv * 16 + lr;
            const int colb = ks1 * 64 + lk * 16;
            const h8 vvv = *reinterpret_cast<const h8*>(ot + row * 128 + (colb ^ ((row & 7) << 4)));
            *reinterpret_cast<h8*>(osp +
                ((((size_t)rt * 4 + t) * 16 + h * 2 + ks1) * 64 + lane) * 8) = vvv;
        }
    }
}

extern "C" void kernel_launch(void* const* d_in, const int* in_sizes, int n_in,
                              void* d_out, int out_size, void* d_ws, size_t ws_size,
                              hipStream_t stream)
{
    const float* x = (const float*)d_in[0];
    const float *W[4], *bia[4], *gam[4], *bet[4], *mea[4], *rva[4];
    for (int br = 0; br < 4; ++br) {
        W[br]   = (const float*)d_in[1 + 6 * br + 0];
        bia[br] = (const float*)d_in[1 + 6 * br + 1];
        gam[br] = (const float*)d_in[1 + 6 * br + 2];
        bet[br] = (const float*)d_in[1 + 6 * br + 3];
        mea[br] = (const float*)d_in[1 + 6 * br + 4];
        rva[br] = (const float*)d_in[1 + 6 * br + 5];
    }
    char* ws = (char*)d_ws;
    _Float16* x1 = (_Float16*)(ws + 0);
    _Float16* x2 = (_Float16*)(ws + 16777216);
    _Float16* sq = (_Float16*)(ws + 33554432);
    _Float16* sk = (_Float16*)(ws + 50331648);
    _Float16* sv = (_Float16*)(ws + 67108864);
    _Float16* w1[4], *w2[4];
    for (int br = 0; br < 4; ++br) {
        w1[br] = (_Float16*)(ws + 83886080 + (size_t)br * 1048576);
        w2[br] = (_Float16*)(ws + 83886080 + (size_t)br * 1048576 + 524288);
    }
    _Float16* kvT = (_Float16*)(ws + 16777216);  // aliases x2 (dead after gemm3)
    _Float16* osp = (_Float16*)(ws + 0);         // aliases x1 (dead after gemm3)

    dim3 blk(256);
    split_pack_x<<<dim3(4096), blk, 0, stream>>>(x, x1, x2);
    pack_w_all<<<dim3(512), blk, 0, stream>>>(W[0], W[1], W[2], W[3],
        w1[0], w2[0], w1[1], w2[1], w1[2], w2[2], w1[3], w2[3]);

    gemm3_bn_lif<<<dim3(512, 3), dim3(512), 0, stream>>>(x1, x2,
        w1[0], w2[0], w1[1], w2[1], w1[2], w2[2],
        bia[0], gam[0], bet[0], mea[0], rva[0],
        bia[1], gam[1], bet[1], mea[1], rva[1],
        bia[2], gam[2], bet[2], mea[2], rva[2],
        sq, sk, sv);

    ktv_kernel<<<dim3(T_ * B_ * H_), blk, 0, stream>>>(sk, sv, kvT);
    qkv_mfma_lif<<<dim3(N_ / 64, B_, H_), blk, 0, stream>>>(sq, kvT, osp);

    gemm_p_bn_lif<<<dim3(512), dim3(512), 0, stream>>>(osp, w1[3], w2[3],
        bia[3], gam[3], bet[3], mea[3], rva[3], (float*)d_out);
}

// Round 14
// 157.950 us; speedup vs baseline: 2.0280x; 1.0688x over previous
//
#include <hip/hip_runtime.h>
#include <hip/hip_bf16.h>

typedef _Float16 h8 __attribute__((ext_vector_type(8)));
typedef float f4 __attribute__((ext_vector_type(4)));

#define T_ 4
#define B_ 8
#define N_ 512
#define C_ 512
#define H_ 8
#define D_ 64
#define BNR 4096
#define EPSf 1e-5f
#define F16_MIN_NORM 6.1035156e-05f
#define INV4096 0.000244140625f

// ---- x -> (h1 + 2^-12 * h2) f16 split, packed MFMA-fragment-linear ----
__global__ __launch_bounds__(256)
void split_pack_x(const float* __restrict__ in, _Float16* __restrict__ h1,
                  _Float16* __restrict__ h2)
{
    const int gid = blockIdx.x * 256 + threadIdx.x;    // 1048576 h8-groups
    const int lane = gid & 63;
    const int ks = (gid >> 6) & 15;
    const int t = (gid >> 10) & 3;
    const int rt = gid >> 12;
    const int row = rt * 16 + (lane & 15);
    const size_t src = ((size_t)t * BNR + row) * C_ + ks * 32 + (lane >> 4) * 8;
    const float4 x0 = *reinterpret_cast<const float4*>(in + src);
    const float4 x1 = *reinterpret_cast<const float4*>(in + src + 4);
    h8 a, b;
    #pragma unroll
    for (int j = 0; j < 8; ++j) {
        const float xv = (j < 4) ? (&x0.x)[j] : (&x1.x)[j - 4];
        const float hi = (fabsf(xv) >= F16_MIN_NORM) ? xv : 0.0f;
        const _Float16 h = (_Float16)hi;
        const float r = (xv - (float)h) * 4096.0f;
        a[j] = h; b[j] = (_Float16)r;
    }
    *reinterpret_cast<h8*>(h1 + (size_t)gid * 8) = a;
    *reinterpret_cast<h8*>(h2 + (size_t)gid * 8) = b;
}

// ---- W -> split + MFMA-fragment-linear pack ----
__device__ __forceinline__
void pack_w_one(const float* __restrict__ W, _Float16* __restrict__ Wp1,
                _Float16* __restrict__ Wp2, int gid)
{
    const int lane = gid & 63;
    const int ni = (gid >> 6) & 3;
    const int ks = (gid >> 8) & 15;
    const int ct = gid >> 12;
    const int col = ct * 64 + ni * 16 + (lane & 15);
    const int k = ks * 32 + (lane >> 4) * 8;
    const float* src = W + (size_t)col * C_ + k;
    h8 a, b;
    #pragma unroll
    for (int j = 0; j < 8; ++j) {
        const float xv = src[j];
        const float hi = (fabsf(xv) >= F16_MIN_NORM) ? xv : 0.0f;
        const _Float16 h = (_Float16)hi;
        const float r = (xv - (float)h) * 4096.0f;
        a[j] = h; b[j] = (_Float16)r;
    }
    *reinterpret_cast<h8*>(Wp1 + (size_t)gid * 8) = a;
    *reinterpret_cast<h8*>(Wp2 + (size_t)gid * 8) = b;
}

__global__ __launch_bounds__(256)
void pack_w_all(const float* __restrict__ Wq, const float* __restrict__ Wk,
                const float* __restrict__ Wv, const float* __restrict__ Wp,
                _Float16* q1, _Float16* q2, _Float16* k1, _Float16* k2,
                _Float16* v1, _Float16* v2, _Float16* p1, _Float16* p2)
{
    const int g = blockIdx.x * 256 + threadIdx.x;     // 131072
    const int br = g >> 15;
    const int gid = g & 32767;
    if (br == 0)      pack_w_one(Wq, q1, q2, gid);
    else if (br == 1) pack_w_one(Wk, k1, k2, gid);
    else if (br == 2) pack_w_one(Wv, v1, v2, gid);
    else              pack_w_one(Wp, p1, p2, gid);
}

// ---- gemm3: r11 structure + counted-vmcnt barrier (T4) + A reg-prefetch ----
// Protocol per k-step: s_waitcnt vmcnt(4) retires THIS wave's gll(ks) (it was
// issued before the 4 A(ks) loads); raw s_barrier makes that true block-wide;
// THEN stage W(ks+1)+prefetch A(ks+1) (post-barrier writes keep the depth-2
// W ring race-free, same as r11). gll(ks+1)/A(ks+1) now survive the barrier.
__global__ __launch_bounds__(512, 4)
void gemm3_bn_lif(const _Float16* __restrict__ A1p, const _Float16* __restrict__ A2p,
                  const _Float16* __restrict__ Wq1, const _Float16* __restrict__ Wq2,
                  const _Float16* __restrict__ Wk1, const _Float16* __restrict__ Wk2,
                  const _Float16* __restrict__ Wv1, const _Float16* __restrict__ Wv2,
                  const float* __restrict__ biq, const float* __restrict__ gaq,
                  const float* __restrict__ beq, const float* __restrict__ meq,
                  const float* __restrict__ rvq,
                  const float* __restrict__ bik, const float* __restrict__ gak,
                  const float* __restrict__ bek, const float* __restrict__ mek,
                  const float* __restrict__ rvk,
                  const float* __restrict__ biv, const float* __restrict__ gav,
                  const float* __restrict__ bev, const float* __restrict__ mev,
                  const float* __restrict__ rvv,
                  _Float16* __restrict__ oq, _Float16* __restrict__ ok,
                  _Float16* __restrict__ ov)
{
    __shared__ __align__(16) char wsm[16384];           // 2 x 8KB W dbuf; reused as v-state
    const int br = blockIdx.y;
    const _Float16* W1 = (br == 0) ? Wq1 : (br == 1) ? Wk1 : Wv1;
    const _Float16* W2 = (br == 0) ? Wq2 : (br == 1) ? Wk2 : Wv2;
    const float* bias = (br == 0) ? biq : (br == 1) ? bik : biv;
    const float* gam  = (br == 0) ? gaq : (br == 1) ? gak : gav;
    const float* bet  = (br == 0) ? beq : (br == 1) ? bek : bev;
    const float* mea  = (br == 0) ? meq : (br == 1) ? mek : mev;
    const float* rva  = (br == 0) ? rvq : (br == 1) ? rvk : rvv;
    _Float16* out = (br == 0) ? oq : (br == 1) ? ok : ov;

    const int id = blockIdx.x;
    const int bt = (id & 7) * 8 + ((id >> 3) & 7);      // XCD-aware swizzle
    const int ct = id >> 6;
    const int tid = threadIdx.x;
    const int wave = tid >> 6, lane = tid & 63;
    const int tp = wave & 1, wr = wave >> 1;
    const int rt = bt * 4 + wr;
    const int row0 = bt * 64, col0 = ct * 64;
    const int lr = lane & 15, lk = lane >> 4;

    f4 accA[2][4], accB[2][4];
    #pragma unroll
    for (int ti = 0; ti < 2; ++ti)
        #pragma unroll
        for (int ni = 0; ni < 4; ++ni) { accA[ti][ni] = (f4)0.0f; accB[ti][ni] = (f4)0.0f; }

    const _Float16* aB1 = A1p + (size_t)rt * 32768 + lane * 8;
    const _Float16* aB2 = A2p + (size_t)rt * 32768 + lane * 8;
    const int s_ = wave >> 2, q_ = wave & 3;
    const _Float16* wsrc = (s_ ? W2 : W1) + (size_t)ct * 32768 + q_ * 512 + lane * 8;
    const int wdoff = s_ * 4096 + q_ * 1024;

    auto stageW = [&](int ks, int b) {
        __builtin_amdgcn_global_load_lds(
            (const __attribute__((address_space(1))) unsigned int*)(wsrc + ks * 2048),
            (__attribute__((address_space(3))) unsigned int*)(wsm + b * 8192 + wdoff),
            16, 0, 0);
    };

    // prologue: gll(0) first, THEN A(0) loads (vmcnt(4) relies on this order)
    stageW(0, 0);
    h8 a1c[2], a2c[2];
    #pragma unroll
    for (int ti = 0; ti < 2; ++ti) {
        const int t = tp * 2 + ti;
        a1c[ti] = *reinterpret_cast<const h8*>(aB1 + (t * 16 + 0) * 512);
        a2c[ti] = *reinterpret_cast<const h8*>(aB2 + (t * 16 + 0) * 512);
    }
    #pragma unroll
    for (int ks = 0; ks < 16; ++ks) {
        const int buf = ks & 1;
        // counted wait: >=5 outstanding -> retire gll(ks) (oldest); keep A(ks) in flight
        asm volatile("s_waitcnt vmcnt(4)" ::: "memory");
        __builtin_amdgcn_s_barrier();
        __builtin_amdgcn_sched_barrier(0);
        h8 a1n[2], a2n[2];
        if (ks < 15) {
            stageW(ks + 1, buf ^ 1);                    // post-barrier: W-ring safe
            #pragma unroll
            for (int ti = 0; ti < 2; ++ti) {            // prefetch A[ks+1]
                const int t = tp * 2 + ti;
                a1n[ti] = *reinterpret_cast<const h8*>(aB1 + (t * 16 + ks + 1) * 512);
                a2n[ti] = *reinterpret_cast<const h8*>(aB2 + (t * 16 + ks + 1) * 512);
            }
        }
        const char* wb = wsm + buf * 8192;
        #pragma unroll
        for (int ni = 0; ni < 4; ++ni) {
            const h8 wf1 = *reinterpret_cast<const h8*>(wb + ni * 1024 + lane * 16);
            const h8 wf2 = *reinterpret_cast<const h8*>(wb + 4096 + ni * 1024 + lane * 16);
            #pragma unroll
            for (int ti = 0; ti < 2; ++ti) {
                accA[ti][ni] = __builtin_amdgcn_mfma_f32_16x16x32_f16(a1c[ti], wf1, accA[ti][ni], 0, 0, 0);
                accB[ti][ni] = __builtin_amdgcn_mfma_f32_16x16x32_f16(a1c[ti], wf2, accB[ti][ni], 0, 0, 0);
                accB[ti][ni] = __builtin_amdgcn_mfma_f32_16x16x32_f16(a2c[ti], wf1, accB[ti][ni], 0, 0, 0);
            }
        }
        if (ks < 15) {
            #pragma unroll
            for (int ti = 0; ti < 2; ++ti) { a1c[ti] = a1n[ti]; a2c[ti] = a2n[ti]; }
        }
    }

    // ---- BN + LIF epilogue with t-split handoff via LDS ----
    float* vst = (float*)wsm;
    float sc[4], bi[4], mn[4], be[4];
    #pragma unroll
    for (int ni = 0; ni < 4; ++ni) {
        const int c = col0 + ni * 16 + lr;
        sc[ni] = gam[c] * (1.0f / sqrtf(rva[c] + EPSf));
        bi[ni] = bias[c]; mn[ni] = mea[c]; be[ni] = bet[c];
    }
    __syncthreads();                                    // full drain before vst reuse
    if (tp == 0) {
        #pragma unroll
        for (int ni = 0; ni < 4; ++ni)
            #pragma unroll
            for (int r = 0; r < 4; ++r) {
                const int rl = wr * 16 + lk * 4 + r;
                const int bn = row0 + rl;
                float vm = 0.0f;
                #pragma unroll
                for (int ti = 0; ti < 2; ++ti) {        // t = 0,1
                    const float res = accA[ti][ni][r] + INV4096 * accB[ti][ni][r];
                    const float y = ((res + bi[ni]) - mn[ni]) * sc[ni] + be[ni];
                    vm = vm + (y - vm) * 0.5f;
                    const float s = (vm >= 1.0f) ? 1.0f : 0.0f;
                    vm = (s != 0.0f) ? 0.0f : vm;
                    const int b = bn >> 9, n = bn & 511;
                    out[((((size_t)ti * B_ + b) * H_ + ct) * N_ + n) * D_ + ni * 16 + lr] =
                        (_Float16)s;
                }
                vst[rl * 64 + ni * 16 + lr] = vm;
            }
    }
    __syncthreads();
    if (tp == 1) {
        #pragma unroll
        for (int ni = 0; ni < 4; ++ni)
            #pragma unroll
            for (int r = 0; r < 4; ++r) {
                const int rl = wr * 16 + lk * 4 + r;
                const int bn = row0 + rl;
                float vm = vst[rl * 64 + ni * 16 + lr];
                #pragma unroll
                for (int ti = 0; ti < 2; ++ti) {        // t = 2,3
                    const float res = accA[ti][ni][r] + INV4096 * accB[ti][ni][r];
                    const float y = ((res + bi[ni]) - mn[ni]) * sc[ni] + be[ni];
                    vm = vm + (y - vm) * 0.5f;
                    const float s = (vm >= 1.0f) ? 1.0f : 0.0f;
                    vm = (s != 0.0f) ? 0.0f : vm;
                    const int b = bn >> 9, n = bn & 511;
                    out[((((size_t)(2 + ti) * B_ + b) * H_ + ct) * N_ + n) * D_ + ni * 16 + lr] =
                        (_Float16)s;
                }
            }
    }
}

// ---- p-GEMM (r10 chunked structure, measured good) ----
__global__ __launch_bounds__(512, 4)
void gemm_p_bn_lif(const _Float16* __restrict__ A1p,
                   const _Float16* __restrict__ Wp1, const _Float16* __restrict__ Wp2,
                   const float* __restrict__ bias, const float* __restrict__ gam,
                   const float* __restrict__ bet, const float* __restrict__ mea,
                   const float* __restrict__ rva, float* __restrict__ out_plain)
{
    __shared__ __align__(16) char wsm[65536];
    const int id = blockIdx.x;
    const int bt = (id & 7) * 8 + ((id >> 3) & 7);
    const int ct = id >> 6;
    const int tid = threadIdx.x;
    const int wave = tid >> 6, lane = tid & 63;
    const int tp = wave & 1, wr = wave >> 1;
    const int rt = bt * 4 + wr;
    const int row0 = bt * 64, col0 = ct * 64;
    const int lr = lane & 15, lk = lane >> 4;

    f4 accA[2][4], accB[2][4];
    #pragma unroll
    for (int ti = 0; ti < 2; ++ti)
        #pragma unroll
        for (int ni = 0; ni < 4; ++ni) { accA[ti][ni] = (f4)0.0f; accB[ti][ni] = (f4)0.0f; }

    const _Float16* aB1 = A1p + (size_t)rt * 32768 + lane * 8;
    const int s_ = wave >> 2, q_ = wave & 3;
    const _Float16* wsrc = (s_ ? Wp2 : Wp1) + (size_t)ct * 32768 + q_ * 512 + lane * 8;
    const int wdoff = s_ * 4096 + q_ * 1024;

    auto stageChunk = [&](int c, int b) {
        #pragma unroll
        for (int ksl = 0; ksl < 4; ++ksl) {
            __builtin_amdgcn_global_load_lds(
                (const __attribute__((address_space(1))) unsigned int*)(wsrc + (c * 4 + ksl) * 2048),
                (__attribute__((address_space(3))) unsigned int*)(wsm + b * 32768 + ksl * 8192 + wdoff),
                16, 0, 0);
        }
    };

    stageChunk(0, 0);
    #pragma unroll
    for (int c = 0; c < 4; ++c) {
        const int buf = c & 1;
        __syncthreads();
        if (c < 3) stageChunk(c + 1, buf ^ 1);
        #pragma unroll
        for (int ksl = 0; ksl < 4; ++ksl) {
            const int ks = c * 4 + ksl;
            h8 a1[2];
            #pragma unroll
            for (int ti = 0; ti < 2; ++ti) {
                const int t = tp * 2 + ti;
                a1[ti] = *reinterpret_cast<const h8*>(aB1 + (t * 16 + ks) * 512);
            }
            const char* wb = wsm + buf * 32768 + ksl * 8192;
            #pragma unroll
            for (int ni = 0; ni < 4; ++ni) {
                const h8 wf1 = *reinterpret_cast<const h8*>(wb + ni * 1024 + lane * 16);
                const h8 wf2 = *reinterpret_cast<const h8*>(wb + 4096 + ni * 1024 + lane * 16);
                #pragma unroll
                for (int ti = 0; ti < 2; ++ti) {
                    accA[ti][ni] = __builtin_amdgcn_mfma_f32_16x16x32_f16(a1[ti], wf1, accA[ti][ni], 0, 0, 0);
                    accB[ti][ni] = __builtin_amdgcn_mfma_f32_16x16x32_f16(a1[ti], wf2, accB[ti][ni], 0, 0, 0);
                }
            }
        }
    }

    float* vst = (float*)wsm;
    float sc[4], bi[4], mn[4], be[4];
    #pragma unroll
    for (int ni = 0; ni < 4; ++ni) {
        const int c = col0 + ni * 16 + lr;
        sc[ni] = gam[c] * (1.0f / sqrtf(rva[c] + EPSf));
        bi[ni] = bias[c]; mn[ni] = mea[c]; be[ni] = bet[c];
    }
    __syncthreads();
    if (tp == 0) {
        #pragma unroll
        for (int ni = 0; ni < 4; ++ni)
            #pragma unroll
            for (int r = 0; r < 4; ++r) {
                const int rl = wr * 16 + lk * 4 + r;
                const int bn = row0 + rl;
                float vm = 0.0f;
                #pragma unroll
                for (int ti = 0; ti < 2; ++ti) {        // t = 0,1
                    const float res = accA[ti][ni][r] + INV4096 * accB[ti][ni][r];
                    const float y = ((res + bi[ni]) - mn[ni]) * sc[ni] + be[ni];
                    vm = vm + (y - vm) * 0.5f;
                    const float s = (vm >= 1.0f) ? 1.0f : 0.0f;
                    vm = (s != 0.0f) ? 0.0f : vm;
                    out_plain[((size_t)ti * BNR + bn) * C_ + col0 + ni * 16 + lr] = s;
                }
                vst[rl * 64 + ni * 16 + lr] = vm;
            }
    }
    __syncthreads();
    if (tp == 1) {
        #pragma unroll
        for (int ni = 0; ni < 4; ++ni)
            #pragma unroll
            for (int r = 0; r < 4; ++r) {
                const int rl = wr * 16 + lk * 4 + r;
                const int bn = row0 + rl;
                float vm = vst[rl * 64 + ni * 16 + lr];
                #pragma unroll
                for (int ti = 0; ti < 2; ++ti) {        // t = 2,3
                    const float res = accA[ti][ni][r] + INV4096 * accB[ti][ni][r];
                    const float y = ((res + bi[ni]) - mn[ni]) * sc[ni] + be[ni];
                    vm = vm + (y - vm) * 0.5f;
                    const float s = (vm >= 1.0f) ? 1.0f : 0.0f;
                    vm = (s != 0.0f) ? 0.0f : vm;
                    out_plain[((size_t)(2 + ti) * BNR + bn) * C_ + col0 + ni * 16 + lr] = s;
                }
            }
    }
}

// ---- kvT[d2][d1] = sum_n k[n,d1]*v[n,d2] per (t,b,h); f16 exact (ints <= 512) ----
__global__ __launch_bounds__(256)
void ktv_kernel(const _Float16* __restrict__ sk, const _Float16* __restrict__ sv,
                _Float16* __restrict__ kvT)
{
    __shared__ _Float16 kl[64][64];
    __shared__ _Float16 vl[64][64];
    const int tbh = blockIdx.x;
    const int tid = threadIdx.x;
    const int tx = tid & 15, ty = tid >> 4;
    const size_t base = (size_t)tbh * N_ * D_;
    float acc[4][4] = {};
    for (int n0 = 0; n0 < N_; n0 += 64) {
        __syncthreads();
        #pragma unroll
        for (int p = 0; p < 2; ++p) {
            const int idx = tid + p * 256;
            const int r = idx >> 3, c8 = (idx & 7) * 8;
            *reinterpret_cast<float4*>(&kl[r][c8]) =
                *reinterpret_cast<const float4*>(&sk[base + (size_t)(n0 + r) * D_ + c8]);
            *reinterpret_cast<float4*>(&vl[r][c8]) =
                *reinterpret_cast<const float4*>(&sv[base + (size_t)(n0 + r) * D_ + c8]);
        }
        __syncthreads();
        for (int nn = 0; nn < 64; ++nn) {
            float a[4], b[4];
            #pragma unroll
            for (int i = 0; i < 4; ++i) a[i] = (float)kl[nn][ty * 4 + i];
            #pragma unroll
            for (int j = 0; j < 4; ++j) b[j] = (float)vl[nn][tx * 4 + j];
            #pragma unroll
            for (int i = 0; i < 4; ++i)
                #pragma unroll
                for (int j = 0; j < 4; ++j)
                    acc[i][j] = fmaf(a[i], b[j], acc[i][j]);
        }
    }
    _Float16* out = kvT + (size_t)tbh * 4096;           // [d2][d1] (transposed)
    #pragma unroll
    for (int i = 0; i < 4; ++i)
        #pragma unroll
        for (int j = 0; j < 4; ++j)
            out[(tx * 4 + j) * 64 + ty * 4 + i] = (_Float16)acc[i][j];
}

// ---- o = 0.125 * q @ kv via MFMA (exact integer arith), fused attn-LIF ----
__global__ __launch_bounds__(256)
void qkv_mfma_lif(const _Float16* __restrict__ sq, const _Float16* __restrict__ kvT,
                  _Float16* __restrict__ osp)
{
    __shared__ __align__(16) char ot[8192];             // [64 rows][128B], swizzled
    const int nt = blockIdx.x, b = blockIdx.y, h = blockIdx.z;
    const int tid = threadIdx.x;
    const int wv = tid >> 6, lane = tid & 63;
    const int lr = lane & 15, lk = lane >> 4;
    const int n0 = nt * 64;

    f4 vst[4];
    #pragma unroll
    for (int ni = 0; ni < 4; ++ni) vst[ni] = (f4)0.0f;

    for (int t = 0; t < T_; ++t) {
        const int tbh = (t * B_ + b) * H_ + h;
        const _Float16* qb = sq + ((size_t)tbh * N_ + n0 + wv * 16 + lr) * D_;
        const h8 a0 = *reinterpret_cast<const h8*>(qb + lk * 8);
        const h8 a1 = *reinterpret_cast<const h8*>(qb + 32 + lk * 8);
        const _Float16* kb = kvT + (size_t)tbh * 4096 + lr * 64 + lk * 8;
        f4 acc[4];
        #pragma unroll
        for (int ni = 0; ni < 4; ++ni) {
            const _Float16* kbn = kb + ni * 1024;
            const h8 b0 = *reinterpret_cast<const h8*>(kbn);
            const h8 b1 = *reinterpret_cast<const h8*>(kbn + 32);
            f4 a = (f4)0.0f;
            a = __builtin_amdgcn_mfma_f32_16x16x32_f16(a0, b0, a, 0, 0, 0);
            a = __builtin_amdgcn_mfma_f32_16x16x32_f16(a1, b1, a, 0, 0, 0);
            acc[ni] = a;
        }
        #pragma unroll
        for (int ni = 0; ni < 4; ++ni)
            #pragma unroll
            for (int r = 0; r < 4; ++r) {
                const float y = 0.125f * acc[ni][r];    // exact
                float vv = vst[ni][r];
                vv = vv + (y - vv) * 0.5f;
                const float s = (vv >= 0.5f) ? 1.0f : 0.0f;
                vst[ni][r] = (s != 0.0f) ? 0.0f : vv;
                const int row = wv * 16 + lk * 4 + r;
                const int colb = (ni * 16 + lr) * 2;
                *(_Float16*)(ot + row * 128 + (colb ^ ((row & 7) << 4))) = (_Float16)s;
            }
        const int rt = b * 32 + nt * 4 + wv;
        #pragma unroll
        for (int ks1 = 0; ks1 < 2; ++ks1) {
            const int row = wv * 16 + lr;
            const int colb = ks1 * 64 + lk * 16;
            const h8 vvv = *reinterpret_cast<const h8*>(ot + row * 128 + (colb ^ ((row & 7) << 4)));
            *reinterpret_cast<h8*>(osp +
                ((((size_t)rt * 4 + t) * 16 + h * 2 + ks1) * 64 + lane) * 8) = vvv;
        }
    }
}

extern "C" void kernel_launch(void* const* d_in, const int* in_sizes, int n_in,
                              void* d_out, int out_size, void* d_ws, size_t ws_size,
                              hipStream_t stream)
{
    const float* x = (const float*)d_in[0];
    const float *W[4], *bia[4], *gam[4], *bet[4], *mea[4], *rva[4];
    for (int br = 0; br < 4; ++br) {
        W[br]   = (const float*)d_in[1 + 6 * br + 0];
        bia[br] = (const float*)d_in[1 + 6 * br + 1];
        gam[br] = (const float*)d_in[1 + 6 * br + 2];
        bet[br] = (const float*)d_in[1 + 6 * br + 3];
        mea[br] = (const float*)d_in[1 + 6 * br + 4];
        rva[br] = (const float*)d_in[1 + 6 * br + 5];
    }
    char* ws = (char*)d_ws;
    _Float16* x1 = (_Float16*)(ws + 0);
    _Float16* x2 = (_Float16*)(ws + 16777216);
    _Float16* sq = (_Float16*)(ws + 33554432);
    _Float16* sk = (_Float16*)(ws + 50331648);
    _Float16* sv = (_Float16*)(ws + 67108864);
    _Float16* w1[4], *w2[4];
    for (int br = 0; br < 4; ++br) {
        w1[br] = (_Float16*)(ws + 83886080 + (size_t)br * 1048576);
        w2[br] = (_Float16*)(ws + 83886080 + (size_t)br * 1048576 + 524288);
    }
    _Float16* kvT = (_Float16*)(ws + 16777216);  // aliases x2 (dead after gemm3)
    _Float16* osp = (_Float16*)(ws + 0);         // aliases x1 (dead after gemm3)

    dim3 blk(256);
    split_pack_x<<<dim3(4096), blk, 0, stream>>>(x, x1, x2);
    pack_w_all<<<dim3(512), blk, 0, stream>>>(W[0], W[1], W[2], W[3],
        w1[0], w2[0], w1[1], w2[1], w1[2], w2[2], w1[3], w2[3]);

    gemm3_bn_lif<<<dim3(512, 3), dim3(512), 0, stream>>>(x1, x2,
        w1[0], w2[0], w1[1], w2[1], w1[2], w2[2],
        bia[0], gam[0], bet[0], mea[0], rva[0],
        bia[1], gam[1], bet[1], mea[1], rva[1],
        bia[2], gam[2], bet[2], mea[2], rva[2],
        sq, sk, sv);

    ktv_kernel<<<dim3(T_ * B_ * H_), blk, 0, stream>>>(sk, sv, kvT);
    qkv_mfma_lif<<<dim3(N_ / 64, B_, H_), blk, 0, stream>>>(sq, kvT, osp);

    gemm_p_bn_lif<<<dim3(512), dim3(512), 0, stream>>>(osp, w1[3], w2[3],
        bia[3], gam[3], bet[3], mea[3], rva[3], (float*)d_out);
}

// Round 15
// 136.782 us; speedup vs baseline: 2.3418x; 1.1548x over previous
//
#include <hip/hip_runtime.h>
#include <hip/hip_bf16.h>

typedef _Float16 h8 __attribute__((ext_vector_type(8)));
typedef float f4 __attribute__((ext_vector_type(4)));

#define T_ 4
#define B_ 8
#define N_ 512
#define C_ 512
#define H_ 8
#define D_ 64
#define BNR 4096
#define EPSf 1e-5f
#define F16_MIN_NORM 6.1035156e-05f
#define INV4096 0.000244140625f

// ---- x -> (h1 + 2^-12 * h2) f16 split, packed MFMA-fragment-linear ----
__global__ __launch_bounds__(256)
void split_pack_x(const float* __restrict__ in, _Float16* __restrict__ h1,
                  _Float16* __restrict__ h2)
{
    const int gid = blockIdx.x * 256 + threadIdx.x;    // 1048576 h8-groups
    const int lane = gid & 63;
    const int ks = (gid >> 6) & 15;
    const int t = (gid >> 10) & 3;
    const int rt = gid >> 12;
    const int row = rt * 16 + (lane & 15);
    const size_t src = ((size_t)t * BNR + row) * C_ + ks * 32 + (lane >> 4) * 8;
    const float4 x0 = *reinterpret_cast<const float4*>(in + src);
    const float4 x1 = *reinterpret_cast<const float4*>(in + src + 4);
    h8 a, b;
    #pragma unroll
    for (int j = 0; j < 8; ++j) {
        const float xv = (j < 4) ? (&x0.x)[j] : (&x1.x)[j - 4];
        const float hi = (fabsf(xv) >= F16_MIN_NORM) ? xv : 0.0f;
        const _Float16 h = (_Float16)hi;
        const float r = (xv - (float)h) * 4096.0f;
        a[j] = h; b[j] = (_Float16)r;
    }
    *reinterpret_cast<h8*>(h1 + (size_t)gid * 8) = a;
    *reinterpret_cast<h8*>(h2 + (size_t)gid * 8) = b;
}

// ---- W -> split + MFMA-fragment-linear pack ----
__device__ __forceinline__
void pack_w_one(const float* __restrict__ W, _Float16* __restrict__ Wp1,
                _Float16* __restrict__ Wp2, int gid)
{
    const int lane = gid & 63;
    const int ni = (gid >> 6) & 3;
    const int ks = (gid >> 8) & 15;
    const int ct = gid >> 12;
    const int col = ct * 64 + ni * 16 + (lane & 15);
    const int k = ks * 32 + (lane >> 4) * 8;
    const float* src = W + (size_t)col * C_ + k;
    h8 a, b;
    #pragma unroll
    for (int j = 0; j < 8; ++j) {
        const float xv = src[j];
        const float hi = (fabsf(xv) >= F16_MIN_NORM) ? xv : 0.0f;
        const _Float16 h = (_Float16)hi;
        const float r = (xv - (float)h) * 4096.0f;
        a[j] = h; b[j] = (_Float16)r;
    }
    *reinterpret_cast<h8*>(Wp1 + (size_t)gid * 8) = a;
    *reinterpret_cast<h8*>(Wp2 + (size_t)gid * 8) = b;
}

__global__ __launch_bounds__(256)
void pack_w_all(const float* __restrict__ Wq, const float* __restrict__ Wk,
                const float* __restrict__ Wv, const float* __restrict__ Wp,
                _Float16* q1, _Float16* q2, _Float16* k1, _Float16* k2,
                _Float16* v1, _Float16* v2, _Float16* p1, _Float16* p2)
{
    const int g = blockIdx.x * 256 + threadIdx.x;     // 131072
    const int br = g >> 15;
    const int gid = g & 32767;
    if (br == 0)      pack_w_one(Wq, q1, q2, gid);
    else if (br == 1) pack_w_one(Wk, k1, k2, gid);
    else if (br == 2) pack_w_one(Wv, v1, v2, gid);
    else              pack_w_one(Wp, p1, p2, gid);
}

// ---- gemm3: r14 structure (counted-vmcnt barrier + A reg-prefetch) ----
__global__ __launch_bounds__(512, 4)
void gemm3_bn_lif(const _Float16* __restrict__ A1p, const _Float16* __restrict__ A2p,
                  const _Float16* __restrict__ Wq1, const _Float16* __restrict__ Wq2,
                  const _Float16* __restrict__ Wk1, const _Float16* __restrict__ Wk2,
                  const _Float16* __restrict__ Wv1, const _Float16* __restrict__ Wv2,
                  const float* __restrict__ biq, const float* __restrict__ gaq,
                  const float* __restrict__ beq, const float* __restrict__ meq,
                  const float* __restrict__ rvq,
                  const float* __restrict__ bik, const float* __restrict__ gak,
                  const float* __restrict__ bek, const float* __restrict__ mek,
                  const float* __restrict__ rvk,
                  const float* __restrict__ biv, const float* __restrict__ gav,
                  const float* __restrict__ bev, const float* __restrict__ mev,
                  const float* __restrict__ rvv,
                  _Float16* __restrict__ oq, _Float16* __restrict__ ok,
                  _Float16* __restrict__ ov)
{
    __shared__ __align__(16) char wsm[16384];           // 2 x 8KB W dbuf; reused as v-state
    const int br = blockIdx.y;
    const _Float16* W1 = (br == 0) ? Wq1 : (br == 1) ? Wk1 : Wv1;
    const _Float16* W2 = (br == 0) ? Wq2 : (br == 1) ? Wk2 : Wv2;
    const float* bias = (br == 0) ? biq : (br == 1) ? bik : biv;
    const float* gam  = (br == 0) ? gaq : (br == 1) ? gak : gav;
    const float* bet  = (br == 0) ? beq : (br == 1) ? bek : bev;
    const float* mea  = (br == 0) ? meq : (br == 1) ? mek : mev;
    const float* rva  = (br == 0) ? rvq : (br == 1) ? rvk : rvv;
    _Float16* out = (br == 0) ? oq : (br == 1) ? ok : ov;

    const int id = blockIdx.x;
    const int bt = (id & 7) * 8 + ((id >> 3) & 7);      // XCD-aware swizzle
    const int ct = id >> 6;
    const int tid = threadIdx.x;
    const int wave = tid >> 6, lane = tid & 63;
    const int tp = wave & 1, wr = wave >> 1;
    const int rt = bt * 4 + wr;
    const int row0 = bt * 64, col0 = ct * 64;
    const int lr = lane & 15, lk = lane >> 4;

    f4 accA[2][4], accB[2][4];
    #pragma unroll
    for (int ti = 0; ti < 2; ++ti)
        #pragma unroll
        for (int ni = 0; ni < 4; ++ni) { accA[ti][ni] = (f4)0.0f; accB[ti][ni] = (f4)0.0f; }

    const _Float16* aB1 = A1p + (size_t)rt * 32768 + lane * 8;
    const _Float16* aB2 = A2p + (size_t)rt * 32768 + lane * 8;
    const int s_ = wave >> 2, q_ = wave & 3;
    const _Float16* wsrc = (s_ ? W2 : W1) + (size_t)ct * 32768 + q_ * 512 + lane * 8;
    const int wdoff = s_ * 4096 + q_ * 1024;

    auto stageW = [&](int ks, int b) {
        __builtin_amdgcn_global_load_lds(
            (const __attribute__((address_space(1))) unsigned int*)(wsrc + ks * 2048),
            (__attribute__((address_space(3))) unsigned int*)(wsm + b * 8192 + wdoff),
            16, 0, 0);
    };

    // prologue: gll(0) first, THEN A(0) loads (vmcnt(4) relies on this order)
    stageW(0, 0);
    h8 a1c[2], a2c[2];
    #pragma unroll
    for (int ti = 0; ti < 2; ++ti) {
        const int t = tp * 2 + ti;
        a1c[ti] = *reinterpret_cast<const h8*>(aB1 + (t * 16 + 0) * 512);
        a2c[ti] = *reinterpret_cast<const h8*>(aB2 + (t * 16 + 0) * 512);
    }
    #pragma unroll
    for (int ks = 0; ks < 16; ++ks) {
        const int buf = ks & 1;
        asm volatile("s_waitcnt vmcnt(4)" ::: "memory");
        __builtin_amdgcn_s_barrier();
        __builtin_amdgcn_sched_barrier(0);
        h8 a1n[2], a2n[2];
        if (ks < 15) {
            stageW(ks + 1, buf ^ 1);                    // post-barrier: W-ring safe
            #pragma unroll
            for (int ti = 0; ti < 2; ++ti) {            // prefetch A[ks+1]
                const int t = tp * 2 + ti;
                a1n[ti] = *reinterpret_cast<const h8*>(aB1 + (t * 16 + ks + 1) * 512);
                a2n[ti] = *reinterpret_cast<const h8*>(aB2 + (t * 16 + ks + 1) * 512);
            }
        }
        const char* wb = wsm + buf * 8192;
        #pragma unroll
        for (int ni = 0; ni < 4; ++ni) {
            const h8 wf1 = *reinterpret_cast<const h8*>(wb + ni * 1024 + lane * 16);
            const h8 wf2 = *reinterpret_cast<const h8*>(wb + 4096 + ni * 1024 + lane * 16);
            #pragma unroll
            for (int ti = 0; ti < 2; ++ti) {
                accA[ti][ni] = __builtin_amdgcn_mfma_f32_16x16x32_f16(a1c[ti], wf1, accA[ti][ni], 0, 0, 0);
                accB[ti][ni] = __builtin_amdgcn_mfma_f32_16x16x32_f16(a1c[ti], wf2, accB[ti][ni], 0, 0, 0);
                accB[ti][ni] = __builtin_amdgcn_mfma_f32_16x16x32_f16(a2c[ti], wf1, accB[ti][ni], 0, 0, 0);
            }
        }
        if (ks < 15) {
            #pragma unroll
            for (int ti = 0; ti < 2; ++ti) { a1c[ti] = a1n[ti]; a2c[ti] = a2n[ti]; }
        }
    }

    // ---- BN + LIF epilogue with t-split handoff via LDS ----
    float* vst = (float*)wsm;
    float sc[4], bi[4], mn[4], be[4];
    #pragma unroll
    for (int ni = 0; ni < 4; ++ni) {
        const int c = col0 + ni * 16 + lr;
        sc[ni] = gam[c] * (1.0f / sqrtf(rva[c] + EPSf));
        bi[ni] = bias[c]; mn[ni] = mea[c]; be[ni] = bet[c];
    }
    __syncthreads();                                    // full drain before vst reuse
    if (tp == 0) {
        #pragma unroll
        for (int ni = 0; ni < 4; ++ni)
            #pragma unroll
            for (int r = 0; r < 4; ++r) {
                const int rl = wr * 16 + lk * 4 + r;
                const int bn = row0 + rl;
                float vm = 0.0f;
                #pragma unroll
                for (int ti = 0; ti < 2; ++ti) {        // t = 0,1
                    const float res = accA[ti][ni][r] + INV4096 * accB[ti][ni][r];
                    const float y = ((res + bi[ni]) - mn[ni]) * sc[ni] + be[ni];
                    vm = vm + (y - vm) * 0.5f;
                    const float s = (vm >= 1.0f) ? 1.0f : 0.0f;
                    vm = (s != 0.0f) ? 0.0f : vm;
                    const int b = bn >> 9, n = bn & 511;
                    out[((((size_t)ti * B_ + b) * H_ + ct) * N_ + n) * D_ + ni * 16 + lr] =
                        (_Float16)s;
                }
                vst[rl * 64 + ni * 16 + lr] = vm;
            }
    }
    __syncthreads();
    if (tp == 1) {
        #pragma unroll
        for (int ni = 0; ni < 4; ++ni)
            #pragma unroll
            for (int r = 0; r < 4; ++r) {
                const int rl = wr * 16 + lk * 4 + r;
                const int bn = row0 + rl;
                float vm = vst[rl * 64 + ni * 16 + lr];
                #pragma unroll
                for (int ti = 0; ti < 2; ++ti) {        // t = 2,3
                    const float res = accA[ti][ni][r] + INV4096 * accB[ti][ni][r];
                    const float y = ((res + bi[ni]) - mn[ni]) * sc[ni] + be[ni];
                    vm = vm + (y - vm) * 0.5f;
                    const float s = (vm >= 1.0f) ? 1.0f : 0.0f;
                    vm = (s != 0.0f) ? 0.0f : vm;
                    const int b = bn >> 9, n = bn & 511;
                    out[((((size_t)(2 + ti) * B_ + b) * H_ + ct) * N_ + n) * D_ + ni * 16 + lr] =
                        (_Float16)s;
                }
            }
    }
}

// ---- p-GEMM: ported to gemm3's T4 structure (per-ks W stage, vmcnt(2)) ----
// Issue order per step: gll(ks) then 2 A-loads -> wait vmcnt(2) retires gll
// only; gll(ks+1)/A(ks+1) stay in flight across the raw barrier.
__global__ __launch_bounds__(512, 4)
void gemm_p_bn_lif(const _Float16* __restrict__ A1p,
                   const _Float16* __restrict__ Wp1, const _Float16* __restrict__ Wp2,
                   const float* __restrict__ bias, const float* __restrict__ gam,
                   const float* __restrict__ bet, const float* __restrict__ mea,
                   const float* __restrict__ rva, float* __restrict__ out_plain)
{
    __shared__ __align__(16) char wsm[16384];
    const int id = blockIdx.x;
    const int bt = (id & 7) * 8 + ((id >> 3) & 7);
    const int ct = id >> 6;
    const int tid = threadIdx.x;
    const int wave = tid >> 6, lane = tid & 63;
    const int tp = wave & 1, wr = wave >> 1;
    const int rt = bt * 4 + wr;
    const int row0 = bt * 64, col0 = ct * 64;
    const int lr = lane & 15, lk = lane >> 4;

    f4 accA[2][4], accB[2][4];
    #pragma unroll
    for (int ti = 0; ti < 2; ++ti)
        #pragma unroll
        for (int ni = 0; ni < 4; ++ni) { accA[ti][ni] = (f4)0.0f; accB[ti][ni] = (f4)0.0f; }

    const _Float16* aB1 = A1p + (size_t)rt * 32768 + lane * 8;
    const int s_ = wave >> 2, q_ = wave & 3;
    const _Float16* wsrc = (s_ ? Wp2 : Wp1) + (size_t)ct * 32768 + q_ * 512 + lane * 8;
    const int wdoff = s_ * 4096 + q_ * 1024;

    auto stageW = [&](int ks, int b) {
        __builtin_amdgcn_global_load_lds(
            (const __attribute__((address_space(1))) unsigned int*)(wsrc + ks * 2048),
            (__attribute__((address_space(3))) unsigned int*)(wsm + b * 8192 + wdoff),
            16, 0, 0);
    };

    stageW(0, 0);
    h8 a1c[2];
    #pragma unroll
    for (int ti = 0; ti < 2; ++ti) {
        const int t = tp * 2 + ti;
        a1c[ti] = *reinterpret_cast<const h8*>(aB1 + (t * 16 + 0) * 512);
    }
    #pragma unroll
    for (int ks = 0; ks < 16; ++ks) {
        const int buf = ks & 1;
        asm volatile("s_waitcnt vmcnt(2)" ::: "memory");
        __builtin_amdgcn_s_barrier();
        __builtin_amdgcn_sched_barrier(0);
        h8 a1n[2];
        if (ks < 15) {
            stageW(ks + 1, buf ^ 1);
            #pragma unroll
            for (int ti = 0; ti < 2; ++ti) {
                const int t = tp * 2 + ti;
                a1n[ti] = *reinterpret_cast<const h8*>(aB1 + (t * 16 + ks + 1) * 512);
            }
        }
        const char* wb = wsm + buf * 8192;
        #pragma unroll
        for (int ni = 0; ni < 4; ++ni) {
            const h8 wf1 = *reinterpret_cast<const h8*>(wb + ni * 1024 + lane * 16);
            const h8 wf2 = *reinterpret_cast<const h8*>(wb + 4096 + ni * 1024 + lane * 16);
            #pragma unroll
            for (int ti = 0; ti < 2; ++ti) {
                accA[ti][ni] = __builtin_amdgcn_mfma_f32_16x16x32_f16(a1c[ti], wf1, accA[ti][ni], 0, 0, 0);
                accB[ti][ni] = __builtin_amdgcn_mfma_f32_16x16x32_f16(a1c[ti], wf2, accB[ti][ni], 0, 0, 0);
            }
        }
        if (ks < 15) {
            #pragma unroll
            for (int ti = 0; ti < 2; ++ti) a1c[ti] = a1n[ti];
        }
    }

    float* vst = (float*)wsm;
    float sc[4], bi[4], mn[4], be[4];
    #pragma unroll
    for (int ni = 0; ni < 4; ++ni) {
        const int c = col0 + ni * 16 + lr;
        sc[ni] = gam[c] * (1.0f / sqrtf(rva[c] + EPSf));
        bi[ni] = bias[c]; mn[ni] = mea[c]; be[ni] = bet[c];
    }
    __syncthreads();
    if (tp == 0) {
        #pragma unroll
        for (int ni = 0; ni < 4; ++ni)
            #pragma unroll
            for (int r = 0; r < 4; ++r) {
                const int rl = wr * 16 + lk * 4 + r;
                const int bn = row0 + rl;
                float vm = 0.0f;
                #pragma unroll
                for (int ti = 0; ti < 2; ++ti) {        // t = 0,1
                    const float res = accA[ti][ni][r] + INV4096 * accB[ti][ni][r];
                    const float y = ((res + bi[ni]) - mn[ni]) * sc[ni] + be[ni];
                    vm = vm + (y - vm) * 0.5f;
                    const float s = (vm >= 1.0f) ? 1.0f : 0.0f;
                    vm = (s != 0.0f) ? 0.0f : vm;
                    out_plain[((size_t)ti * BNR + bn) * C_ + col0 + ni * 16 + lr] = s;
                }
                vst[rl * 64 + ni * 16 + lr] = vm;
            }
    }
    __syncthreads();
    if (tp == 1) {
        #pragma unroll
        for (int ni = 0; ni < 4; ++ni)
            #pragma unroll
            for (int r = 0; r < 4; ++r) {
                const int rl = wr * 16 + lk * 4 + r;
                const int bn = row0 + rl;
                float vm = vst[rl * 64 + ni * 16 + lr];
                #pragma unroll
                for (int ti = 0; ti < 2; ++ti) {        // t = 2,3
                    const float res = accA[ti][ni][r] + INV4096 * accB[ti][ni][r];
                    const float y = ((res + bi[ni]) - mn[ni]) * sc[ni] + be[ni];
                    vm = vm + (y - vm) * 0.5f;
                    const float s = (vm >= 1.0f) ? 1.0f : 0.0f;
                    vm = (s != 0.0f) ? 0.0f : vm;
                    out_plain[((size_t)(2 + ti) * BNR + bn) * C_ + col0 + ni * 16 + lr] = s;
                }
            }
    }
}

// ---- ktv via MFMA: kvT[d2][d1] = sum_n v[n,d2]*k[n,d1], exact integers ----
// Stage k,v 64-n chunks TRANSPOSED into LDS (kT/vT[d][n], XOR-swizzled n-groups),
// then mfma(A=vT frag, B=kT frag) -> D[d2][d1]. 64 MFMA/wave total.
__global__ __launch_bounds__(256)
void ktv_mfma(const _Float16* __restrict__ sk, const _Float16* __restrict__ sv,
              _Float16* __restrict__ kvT)
{
    __shared__ _Float16 kT[64][64];
    __shared__ _Float16 vT[64][64];
    const int tbh = blockIdx.x;
    const int tid = threadIdx.x;
    const int wv = tid >> 6, lane = tid & 63;
    const int lr = lane & 15, lk = lane >> 4;
    const size_t base = (size_t)tbh * N_ * D_;

    f4 acc[4];
    #pragma unroll
    for (int ni = 0; ni < 4; ++ni) acc[ni] = (f4)0.0f;

    for (int n0 = 0; n0 < N_; n0 += 64) {
        __syncthreads();                                // prev chunk reads done
        #pragma unroll
        for (int p = 0; p < 2; ++p) {
            const int idx = p * 256 + tid;              // 512 = 64 n x 8 d-groups
            const int n = idx >> 3, d0 = (idx & 7) * 8;
            const h8 kv_ = *reinterpret_cast<const h8*>(&sk[base + (size_t)(n0 + n) * D_ + d0]);
            const h8 vv_ = *reinterpret_cast<const h8*>(&sv[base + (size_t)(n0 + n) * D_ + d0]);
            #pragma unroll
            for (int j = 0; j < 8; ++j) {
                const int d = d0 + j;
                const int nsw = (((n >> 3) ^ (d & 7)) << 3) | (n & 7);
                kT[d][nsw] = kv_[j];
                vT[d][nsw] = vv_[j];
            }
        }
        __syncthreads();
        #pragma unroll
        for (int ks2 = 0; ks2 < 2; ++ks2) {
            const int g0 = ks2 * 4 + lk;                // n-group 0..7
            const int d2 = wv * 16 + lr;
            const h8 av = *reinterpret_cast<const h8*>(&vT[d2][(g0 ^ (d2 & 7)) << 3]);
            #pragma unroll
            for (int ni = 0; ni < 4; ++ni) {
                const int d1 = ni * 16 + lr;
                const h8 bk = *reinterpret_cast<const h8*>(&kT[d1][(g0 ^ (d1 & 7)) << 3]);
                acc[ni] = __builtin_amdgcn_mfma_f32_16x16x32_f16(av, bk, acc[ni], 0, 0, 0);
            }
        }
    }
    _Float16* out = kvT + (size_t)tbh * 4096;           // [d2][d1]
    #pragma unroll
    for (int ni = 0; ni < 4; ++ni)
        #pragma unroll
        for (int r = 0; r < 4; ++r) {
            const int d2 = wv * 16 + lk * 4 + r;        // C-layout: row=(l>>4)*4+r
            const int d1 = ni * 16 + lr;                // col=l&15
            out[d2 * 64 + d1] = (_Float16)acc[ni][r];
        }
}

// ---- o = 0.125 * q @ kv via MFMA (exact integer arith), fused attn-LIF ----
__global__ __launch_bounds__(256)
void qkv_mfma_lif(const _Float16* __restrict__ sq, const _Float16* __restrict__ kvT,
                  _Float16* __restrict__ osp)
{
    __shared__ __align__(16) char ot[8192];             // [64 rows][128B], swizzled
    const int nt = blockIdx.x, b = blockIdx.y, h = blockIdx.z;
    const int tid = threadIdx.x;
    const int wv = tid >> 6, lane = tid & 63;
    const int lr = lane & 15, lk = lane >> 4;
    const int n0 = nt * 64;

    f4 vst[4];
    #pragma unroll
    for (int ni = 0; ni < 4; ++ni) vst[ni] = (f4)0.0f;

    for (int t = 0; t < T_; ++t) {
        const int tbh = (t * B_ + b) * H_ + h;
        const _Float16* qb = sq + ((size_t)tbh * N_ + n0 + wv * 16 + lr) * D_;
        const h8 a0 = *reinterpret_cast<const h8*>(qb + lk * 8);
        const h8 a1 = *reinterpret_cast<const h8*>(qb + 32 + lk * 8);
        const _Float16* kb = kvT + (size_t)tbh * 4096 + lr * 64 + lk * 8;
        f4 acc[4];
        #pragma unroll
        for (int ni = 0; ni < 4; ++ni) {
            const _Float16* kbn = kb + ni * 1024;
            const h8 b0 = *reinterpret_cast<const h8*>(kbn);
            const h8 b1 = *reinterpret_cast<const h8*>(kbn + 32);
            f4 a = (f4)0.0f;
            a = __builtin_amdgcn_mfma_f32_16x16x32_f16(a0, b0, a, 0, 0, 0);
            a = __builtin_amdgcn_mfma_f32_16x16x32_f16(a1, b1, a, 0, 0, 0);
            acc[ni] = a;
        }
        #pragma unroll
        for (int ni = 0; ni < 4; ++ni)
            #pragma unroll
            for (int r = 0; r < 4; ++r) {
                const float y = 0.125f * acc[ni][r];    // exact
                float vv = vst[ni][r];
                vv = vv + (y - vv) * 0.5f;
                const float s = (vv >= 0.5f) ? 1.0f : 0.0f;
                vst[ni][r] = (s != 0.0f) ? 0.0f : vv;
                const int row = wv * 16 + lk * 4 + r;
                const int colb = (ni * 16 + lr) * 2;
                *(_Float16*)(ot + row * 128 + (colb ^ ((row & 7) << 4))) = (_Float16)s;
            }
        const int rt = b * 32 + nt * 4 + wv;
        #pragma unroll
        for (int ks1 = 0; ks1 < 2; ++ks1) {
            const int row = wv * 16 + lr;
            const int colb = ks1 * 64 + lk * 16;
            const h8 vvv = *reinterpret_cast<const h8*>(ot + row * 128 + (colb ^ ((row & 7) << 4)));
            *reinterpret_cast<h8*>(osp +
                ((((size_t)rt * 4 + t) * 16 + h * 2 + ks1) * 64 + lane) * 8) = vvv;
        }
    }
}

extern "C" void kernel_launch(void* const* d_in, const int* in_sizes, int n_in,
                              void* d_out, int out_size, void* d_ws, size_t ws_size,
                              hipStream_t stream)
{
    const float* x = (const float*)d_in[0];
    const float *W[4], *bia[4], *gam[4], *bet[4], *mea[4], *rva[4];
    for (int br = 0; br < 4; ++br) {
        W[br]   = (const float*)d_in[1 + 6 * br + 0];
        bia[br] = (const float*)d_in[1 + 6 * br + 1];
        gam[br] = (const float*)d_in[1 + 6 * br + 2];
        bet[br] = (const float*)d_in[1 + 6 * br + 3];
        mea[br] = (const float*)d_in[1 + 6 * br + 4];
        rva[br] = (const float*)d_in[1 + 6 * br + 5];
    }
    char* ws = (char*)d_ws;
    _Float16* x1 = (_Float16*)(ws + 0);
    _Float16* x2 = (_Float16*)(ws + 16777216);
    _Float16* sq = (_Float16*)(ws + 33554432);
    _Float16* sk = (_Float16*)(ws + 50331648);
    _Float16* sv = (_Float16*)(ws + 67108864);
    _Float16* w1[4], *w2[4];
    for (int br = 0; br < 4; ++br) {
        w1[br] = (_Float16*)(ws + 83886080 + (size_t)br * 1048576);
        w2[br] = (_Float16*)(ws + 83886080 + (size_t)br * 1048576 + 524288);
    }
    _Float16* kvT = (_Float16*)(ws + 16777216);  // aliases x2 (dead after gemm3)
    _Float16* osp = (_Float16*)(ws + 0);         // aliases x1 (dead after gemm3)

    dim3 blk(256);
    split_pack_x<<<dim3(4096), blk, 0, stream>>>(x, x1, x2);
    pack_w_all<<<dim3(512), blk, 0, stream>>>(W[0], W[1], W[2], W[3],
        w1[0], w2[0], w1[1], w2[1], w1[2], w2[2], w1[3], w2[3]);

    gemm3_bn_lif<<<dim3(512, 3), dim3(512), 0, stream>>>(x1, x2,
        w1[0], w2[0], w1[1], w2[1], w1[2], w2[2],
        bia[0], gam[0], bet[0], mea[0], rva[0],
        bia[1], gam[1], bet[1], mea[1], rva[1],
        bia[2], gam[2], bet[2], mea[2], rva[2],
        sq, sk, sv);

    ktv_mfma<<<dim3(T_ * B_ * H_), blk, 0, stream>>>(sk, sv, kvT);
    qkv_mfma_lif<<<dim3(N_ / 64, B_, H_), blk, 0, stream>>>(sq, kvT, osp);

    gemm_p_bn_lif<<<dim3(512), dim3(512), 0, stream>>>(osp, w1[3], w2[3],
        bia[3], gam[3], bet[3], mea[3], rva[3], (float*)d_out);
}